// Round 13
// baseline (865.119 us; speedup 1.0000x reference)
//
#include <hip/hip_runtime.h>
#include <hip/hip_fp16.h>
#include <math.h>

#define NNODES 200000
#define NEDGES 3200000
#define NG     256
#define NB1    98                      // ceil(200000/2048) for deg scan
#define EPB    1024                    // target edges per fused-hop block
#define ECAP   1152                    // LDS edge capacity (EPB + max-degree slack)
#define NB     ((NEDGES + EPB - 1) / EPB)
#define SMASK  0x00FFFFFF

static __device__ __forceinline__ float relu_(float x) { return x > 0.f ? x : 0.f; }
static __device__ __forceinline__ float sigmoid_(float x) { return 1.f / (1.f + expf(-x)); }

static __device__ __forceinline__ unsigned pk2_(float a, float b) {
    union { __half2 h; unsigned u; } x;
    x.h = __floats2half2_rn(a, b);
    return x.u;
}
static __device__ __forceinline__ float2 up2_(unsigned u) {
    union { unsigned u; __half2 h; } x; x.u = u;
    return __half22float2(x.h);
}

// ---------------- node encoder (+ He_s projection table) ----------------
__global__ __launch_bounds__(256) void k_node_enc(
    const float* __restrict__ nodes,
    const float* __restrict__ Wn1, const float* __restrict__ bn1,
    const float* __restrict__ Wn2, const float* __restrict__ bn2,
    const float* __restrict__ He_s,
    float* __restrict__ nbuf, uint4* __restrict__ pproj)
{
    int v = blockIdx.x * 256 + threadIdx.x;
    if (v >= NNODES) return;
    float acc1[32];
#pragma unroll
    for (int j = 0; j < 32; j++) acc1[j] = bn1[j];
    const float4* xp = (const float4*)(nodes + (size_t)v * 128);
#pragma unroll 1
    for (int k4 = 0; k4 < 32; k4++) {
        float4 x = xp[k4];
        const float* w = Wn1 + k4 * 4 * 32;
#pragma unroll
        for (int j = 0; j < 32; j++) acc1[j] = fmaf(x.x, w[j], acc1[j]);
#pragma unroll
        for (int j = 0; j < 32; j++) acc1[j] = fmaf(x.y, w[32 + j], acc1[j]);
#pragma unroll
        for (int j = 0; j < 32; j++) acc1[j] = fmaf(x.z, w[64 + j], acc1[j]);
#pragma unroll
        for (int j = 0; j < 32; j++) acc1[j] = fmaf(x.w, w[96 + j], acc1[j]);
    }
#pragma unroll
    for (int j = 0; j < 32; j++) acc1[j] = relu_(acc1[j]);
    float acc2[16];
#pragma unroll
    for (int j = 0; j < 16; j++) acc2[j] = bn2[j];
#pragma unroll 1
    for (int k = 0; k < 32; k++) {
        const float* w = Wn2 + k * 16;
        float x = acc1[k];
#pragma unroll
        for (int j = 0; j < 16; j++) acc2[j] = fmaf(x, w[j], acc2[j]);
    }
#pragma unroll
    for (int j = 0; j < 16; j++) acc2[j] = relu_(acc2[j]);
    float4* o4 = (float4*)(nbuf + (size_t)v * 16);
    o4[0] = make_float4(acc2[0], acc2[1], acc2[2], acc2[3]);
    o4[1] = make_float4(acc2[4], acc2[5], acc2[6], acc2[7]);
    o4[2] = make_float4(acc2[8], acc2[9], acc2[10], acc2[11]);
    o4[3] = make_float4(acc2[12], acc2[13], acc2[14], acc2[15]);
    float pj[8];
#pragma unroll
    for (int j = 0; j < 8; j++) pj[j] = 0.f;
#pragma unroll
    for (int k = 0; k < 16; k++) {
        const float* w = He_s + k * 8;
#pragma unroll
        for (int j = 0; j < 8; j++) pj[j] = fmaf(acc2[k], w[j], pj[j]);
    }
    uint4 pk;
    pk.x = pk2_(pj[0], pj[1]); pk.y = pk2_(pj[2], pj[3]);
    pk.z = pk2_(pj[4], pj[5]); pk.w = pk2_(pj[6], pj[7]);
    pproj[v] = pk;
}

// ---------------- degree histogram over receivers ----------------
__global__ __launch_bounds__(256) void k_deg(const int* __restrict__ receivers, int* __restrict__ deg)
{
    for (int i = blockIdx.x * 256 + threadIdx.x; i < NEDGES; i += gridDim.x * 256)
        atomicAdd(&deg[receivers[i]], 1);
}

// ---------------- hierarchical exclusive scan of deg -> off, cursor ----------------
__global__ __launch_bounds__(256) void k_scan1(const int* __restrict__ deg, int* __restrict__ bsum)
{
    __shared__ int ts[256];
    int b = blockIdx.x, t = threadIdx.x;
    int base = b * 2048 + t * 8;
    int s = 0;
#pragma unroll
    for (int u = 0; u < 8; u++) { int idx = base + u; if (idx < NNODES) s += deg[idx]; }
    ts[t] = s; __syncthreads();
    for (int ofs = 128; ofs > 0; ofs >>= 1) {
        if (t < ofs) ts[t] += ts[t + ofs];
        __syncthreads();
    }
    if (t == 0) bsum[b] = ts[0];
}

__global__ void k_scan2(const int* __restrict__ bsum, int* __restrict__ bpre)
{
    if (threadIdx.x == 0) {
        int acc = 0;
        for (int i = 0; i < NB1; i++) { bpre[i] = acc; acc += bsum[i]; }
    }
}

__global__ __launch_bounds__(256) void k_scan3(const int* __restrict__ deg, const int* __restrict__ bpre,
                                               int* __restrict__ off, int* __restrict__ cursor)
{
    __shared__ int ts[256];
    int b = blockIdx.x, t = threadIdx.x;
    int base = b * 2048 + t * 8;
    int loc[8]; int s = 0;
#pragma unroll
    for (int u = 0; u < 8; u++) {
        int idx = base + u;
        int d = (idx < NNODES) ? deg[idx] : 0;
        loc[u] = d; s += d;
    }
    ts[t] = s; __syncthreads();
    for (int ofs = 1; ofs < 256; ofs <<= 1) {
        int v = (t >= ofs) ? ts[t - ofs] : 0;
        __syncthreads();
        ts[t] += v;
        __syncthreads();
    }
    int ex = ((t == 0) ? 0 : ts[t - 1]) + bpre[b];
#pragma unroll
    for (int u = 0; u < 8; u++) {
        int idx = base + u;
        if (idx < NNODES) { off[idx] = ex; cursor[idx] = ex; ex += loc[u]; }
    }
    if (b == 0 && t == 0) off[NNODES] = NEDGES;
}

// ---------------- fused permutation + edge encoder + HOP-1 edge update (2x unrolled) ----------
__global__ __launch_bounds__(256) void k_perm_enc(
    const float* __restrict__ edges,
    const int* __restrict__ receivers, const int* __restrict__ senders,
    const int* __restrict__ node_graph,
    const float* __restrict__ We1, const float* __restrict__ be1,
    const float* __restrict__ We2, const float* __restrict__ be2,
    const float* __restrict__ He_e,
    const uint4* __restrict__ pproj, const float* __restrict__ ghe,
    int* __restrict__ cursor, uint4* __restrict__ rec2,
    int* __restrict__ ecnt, float* __restrict__ gsum_e)
{
    __shared__ int hist[NG];
    __shared__ float bins[NG * 8];
    for (int i = threadIdx.x; i < NG; i += 256) hist[i] = 0;
    for (int i = threadIdx.x; i < NG * 8; i += 256) bins[i] = 0.f;
    __syncthreads();
    const int stride = gridDim.x * 256;
    for (int i = blockIdx.x * 256 + threadIdx.x; i < NEDGES; i += 2 * stride) {
        int i2 = i + stride;
        bool v2 = (i2 < NEDGES);
        float accA[8], accB[8];
        int rA = 0, sA = 0, gidA = 0, rB = 0, sB = 0, gidB = 0;
        {
            float x[16];
            const float4* xp = (const float4*)(edges + (size_t)i * 16);
#pragma unroll
            for (int q = 0; q < 4; q++) {
                float4 tt = xp[q];
                x[q * 4] = tt.x; x[q * 4 + 1] = tt.y; x[q * 4 + 2] = tt.z; x[q * 4 + 3] = tt.w;
            }
            float h1[4];
#pragma unroll
            for (int j = 0; j < 4; j++) h1[j] = be1[j];
#pragma unroll
            for (int k = 0; k < 16; k++) {
                const float* w = We1 + k * 4;
#pragma unroll
                for (int j = 0; j < 4; j++) h1[j] = fmaf(x[k], w[j], h1[j]);
            }
#pragma unroll
            for (int j = 0; j < 4; j++) h1[j] = relu_(h1[j]);
            float ev[8];
#pragma unroll
            for (int j = 0; j < 8; j++) ev[j] = be2[j];
#pragma unroll
            for (int k = 0; k < 4; k++) {
                const float* w = We2 + k * 8;
#pragma unroll
                for (int j = 0; j < 8; j++) ev[j] = fmaf(h1[k], w[j], ev[j]);
            }
#pragma unroll
            for (int j = 0; j < 8; j++) ev[j] = relu_(ev[j]);
            rA = receivers[i]; sA = senders[i]; gidA = node_graph[sA];
            uint4 praw = pproj[sA];
            const float4* ghp = (const float4*)(ghe + gidA * 8);
            float4 gh0 = ghp[0], gh1 = ghp[1];
            float2 f;
            f = up2_(praw.x); accA[0] = gh0.x + f.x; accA[1] = gh0.y + f.y;
            f = up2_(praw.y); accA[2] = gh0.z + f.x; accA[3] = gh0.w + f.y;
            f = up2_(praw.z); accA[4] = gh1.x + f.x; accA[5] = gh1.y + f.y;
            f = up2_(praw.w); accA[6] = gh1.z + f.x; accA[7] = gh1.w + f.y;
#pragma unroll
            for (int k = 0; k < 8; k++) {
                const float* w = He_e + k * 8;
#pragma unroll
                for (int j = 0; j < 8; j++) accA[j] = fmaf(ev[k], w[j], accA[j]);
            }
#pragma unroll
            for (int j = 0; j < 8; j++) accA[j] = relu_(accA[j]);
        }
        if (v2) {
            float x[16];
            const float4* xp = (const float4*)(edges + (size_t)i2 * 16);
#pragma unroll
            for (int q = 0; q < 4; q++) {
                float4 tt = xp[q];
                x[q * 4] = tt.x; x[q * 4 + 1] = tt.y; x[q * 4 + 2] = tt.z; x[q * 4 + 3] = tt.w;
            }
            float h1[4];
#pragma unroll
            for (int j = 0; j < 4; j++) h1[j] = be1[j];
#pragma unroll
            for (int k = 0; k < 16; k++) {
                const float* w = We1 + k * 4;
#pragma unroll
                for (int j = 0; j < 4; j++) h1[j] = fmaf(x[k], w[j], h1[j]);
            }
#pragma unroll
            for (int j = 0; j < 4; j++) h1[j] = relu_(h1[j]);
            float ev[8];
#pragma unroll
            for (int j = 0; j < 8; j++) ev[j] = be2[j];
#pragma unroll
            for (int k = 0; k < 4; k++) {
                const float* w = We2 + k * 8;
#pragma unroll
                for (int j = 0; j < 8; j++) ev[j] = fmaf(h1[k], w[j], ev[j]);
            }
#pragma unroll
            for (int j = 0; j < 8; j++) ev[j] = relu_(ev[j]);
            rB = receivers[i2]; sB = senders[i2]; gidB = node_graph[sB];
            uint4 praw = pproj[sB];
            const float4* ghp = (const float4*)(ghe + gidB * 8);
            float4 gh0 = ghp[0], gh1 = ghp[1];
            float2 f;
            f = up2_(praw.x); accB[0] = gh0.x + f.x; accB[1] = gh0.y + f.y;
            f = up2_(praw.y); accB[2] = gh0.z + f.x; accB[3] = gh0.w + f.y;
            f = up2_(praw.z); accB[4] = gh1.x + f.x; accB[5] = gh1.y + f.y;
            f = up2_(praw.w); accB[6] = gh1.z + f.x; accB[7] = gh1.w + f.y;
#pragma unroll
            for (int k = 0; k < 8; k++) {
                const float* w = He_e + k * 8;
#pragma unroll
                for (int j = 0; j < 8; j++) accB[j] = fmaf(ev[k], w[j], accB[j]);
            }
#pragma unroll
            for (int j = 0; j < 8; j++) accB[j] = relu_(accB[j]);
        }
        int posA = atomicAdd(&cursor[rA], 1);
        int posB = v2 ? atomicAdd(&cursor[rB], 1) : 0;
        {
            uint4 pk;
            pk.x = pk2_(accA[0], accA[1]); pk.y = pk2_(accA[2], accA[3]);
            pk.z = pk2_(accA[4], accA[5]); pk.w = pk2_(accA[6], accA[7]);
            rec2[(size_t)posA * 2]     = pk;
            rec2[(size_t)posA * 2 + 1] = make_uint4((unsigned)(sA | (gidA << 24)), 0u, 0u, 0u);
            atomicAdd(&hist[gidA], 1);
#pragma unroll
            for (int j = 0; j < 8; j++) atomicAdd(&bins[gidA * 8 + j], accA[j]);
        }
        if (v2) {
            uint4 pk;
            pk.x = pk2_(accB[0], accB[1]); pk.y = pk2_(accB[2], accB[3]);
            pk.z = pk2_(accB[4], accB[5]); pk.w = pk2_(accB[6], accB[7]);
            rec2[(size_t)posB * 2]     = pk;
            rec2[(size_t)posB * 2 + 1] = make_uint4((unsigned)(sB | (gidB << 24)), 0u, 0u, 0u);
            atomicAdd(&hist[gidB], 1);
#pragma unroll
            for (int j = 0; j < 8; j++) atomicAdd(&bins[gidB * 8 + j], accB[j]);
        }
    }
    __syncthreads();
    for (int i = threadIdx.x; i < NG; i += 256)
        if (hist[i]) atomicAdd(&ecnt[i], hist[i]);
    for (int i = threadIdx.x; i < NG * 8; i += 256) {
        float v = bins[i];
        if (v != 0.f) atomicAdd(&gsum_e[i], v);
    }
}

// ---------------- graph start offsets + per-block receiver ranges (merged) ----------------
__global__ __launch_bounds__(256) void k_aux(const int* __restrict__ ng, const int* __restrict__ off,
                                             int* __restrict__ goff, int* __restrict__ rstart)
{
    int v = blockIdx.x * 256 + threadIdx.x;
    if (v < NNODES) {
        int a = ng[v];
        if (v == 0) { for (int g = 0; g <= a; g++) goff[g] = 0; }
        else { int b = ng[v - 1]; for (int g = b + 1; g <= a; g++) goff[g] = v; }
        if (v == NNODES - 1) { for (int g = a + 1; g <= NG; g++) goff[g] = NNODES; }
    }
    if (v <= NB) {
        if (v == NB) { rstart[NB] = NNODES; }
        else {
            int target = v * EPB;
            int lo = 0, hi = NNODES;
            while (lo < hi) { int mid = (lo + hi) >> 1; if (off[mid] >= target) hi = mid; else lo = mid + 1; }
            rstart[v] = lo;
        }
    }
}

// ---------------- per-graph node sum via contiguous ranges ----------------
__global__ __launch_bounds__(256) void k_gsum_nodes(
    const float* __restrict__ nbuf, const int* __restrict__ goff, float* __restrict__ gsum_n)
{
    __shared__ float red[256 * 16];
    int g = blockIdx.x, t = threadIdx.x;
    int s = goff[g], eN = goff[g + 1];
    float acc[16];
#pragma unroll
    for (int j = 0; j < 16; j++) acc[j] = 0.f;
    for (int v = s + t; v < eN; v += 256) {
        const float4* p = (const float4*)(nbuf + (size_t)v * 16);
#pragma unroll
        for (int q = 0; q < 4; q++) {
            float4 x = p[q];
            acc[q * 4] += x.x; acc[q * 4 + 1] += x.y; acc[q * 4 + 2] += x.z; acc[q * 4 + 3] += x.w;
        }
    }
#pragma unroll
    for (int j = 0; j < 16; j++) red[t * 16 + j] = acc[j];
    __syncthreads();
    for (int ofs = 128; ofs > 0; ofs >>= 1) {
        if (t < ofs) {
#pragma unroll
            for (int j = 0; j < 16; j++) red[t * 16 + j] += red[(t + ofs) * 16 + j];
        }
        __syncthreads();
    }
    if (t < 16) gsum_n[g * 16 + t] = red[t];
}

// ---------------- g encoder (+ per-graph folded tables ghe/ghn) ----------------
__global__ void k_g_enc(
    const float* __restrict__ gsum_n, const int* __restrict__ goff,
    const float* __restrict__ Wg2, const float* __restrict__ bg2,
    const float* __restrict__ He_g, const float* __restrict__ He_b,
    const float* __restrict__ Hn_g, const float* __restrict__ Hn_b,
    float* __restrict__ g, float* __restrict__ ghe, float* __restrict__ ghn)
{
    int gi = threadIdx.x;
    float c = 1.f / fmaxf((float)(goff[gi + 1] - goff[gi]), 1.f);
    float nm[16];
#pragma unroll
    for (int k = 0; k < 16; k++) nm[k] = gsum_n[gi * 16 + k] * c;
    float acc[4];
#pragma unroll
    for (int j = 0; j < 4; j++) acc[j] = bg2[j];
#pragma unroll
    for (int k = 0; k < 16; k++) {
        const float* w = Wg2 + k * 4;
#pragma unroll
        for (int j = 0; j < 4; j++) acc[j] = fmaf(nm[k], w[j], acc[j]);
    }
    *(float4*)(g + gi * 4) = make_float4(acc[0], acc[1], acc[2], acc[3]);
    float he[8];
#pragma unroll
    for (int j = 0; j < 8; j++) he[j] = He_b[j];
#pragma unroll
    for (int k = 0; k < 4; k++)
#pragma unroll
        for (int j = 0; j < 8; j++) he[j] = fmaf(acc[k], He_g[k * 8 + j], he[j]);
#pragma unroll
    for (int j = 0; j < 8; j++) ghe[gi * 8 + j] = he[j];
    float hn[16];
#pragma unroll
    for (int j = 0; j < 16; j++) hn[j] = Hn_b[j];
#pragma unroll
    for (int k = 0; k < 4; k++)
#pragma unroll
        for (int j = 0; j < 16; j++) hn[j] = fmaf(acc[k], Hn_g[k * 16 + j], hn[j]);
#pragma unroll
    for (int j = 0; j < 16; j++) ghn[gi * 16 + j] = hn[j];
}

// ---------------- fused hop: edge phase + node phase (LDS segments) ----
// MODE 0: load rec2 (e1 precomputed) into LDS; node phase only; writes pproj_out.
// MODE 1: read rec2 {e1,spack}, compute e2, write e4 + compact spack, bins; writes pproj_out.
// MODE 2: read e4/spack, compute e3, no writes, bins; node phase + readout.
template <int MODE>
__global__ __launch_bounds__(256) void k_hop(
    const uint4* __restrict__ rec2, int* __restrict__ spack,
    const int* __restrict__ off, const int* __restrict__ rstart,
    const int* __restrict__ node_graph,
    uint4* __restrict__ e4, const uint4* __restrict__ pproj, uint4* __restrict__ pproj_out,
    const float* __restrict__ nin, float* __restrict__ nout,
    const float* __restrict__ ghe, const float* __restrict__ ghn,
    const float* __restrict__ He_e, const float* __restrict__ He_s,
    const float* __restrict__ Hn_n, const float* __restrict__ Hn_in,
    float* __restrict__ gsum_e,
    const float* __restrict__ Rn, const float* __restrict__ Rn_b,
    float* __restrict__ out)
{
    __shared__ uint4 ebuf[ECAP];        // 18 KB fp16-packed edge values
    __shared__ float bins[NG * 8];      // 8 KB per-graph edge sums
    int t = threadIdx.x;
    if constexpr (MODE != 0) {
        for (int i = t; i < NG * 8; i += 256) bins[i] = 0.f;
    }
    __syncthreads();

    int b  = blockIdx.x;
    int r0 = rstart[b], r1 = rstart[b + 1];
    int e0 = off[r0],   e1 = off[r1];

    // ---- edge phase ----
    for (int i = e0 + t; i < e1; i += 256) {
        int local = i - e0;
        if constexpr (MODE == 0) {
            if (local < ECAP) ebuf[local] = rec2[(size_t)i * 2];
            continue;
        } else {
            int packed;
            float ev[8];
            if constexpr (MODE == 1) {
                uint4 ea = rec2[(size_t)i * 2];
                uint4 eb = rec2[(size_t)i * 2 + 1];
                packed = (int)eb.x;
                spack[i] = packed;          // compact for hop 3
                float2 f;
                f = up2_(ea.x); ev[0] = f.x; ev[1] = f.y;
                f = up2_(ea.y); ev[2] = f.x; ev[3] = f.y;
                f = up2_(ea.z); ev[4] = f.x; ev[5] = f.y;
                f = up2_(ea.w); ev[6] = f.x; ev[7] = f.y;
            } else {
                packed = spack[i];
                uint4 raw = e4[i];
                float2 f;
                f = up2_(raw.x); ev[0] = f.x; ev[1] = f.y;
                f = up2_(raw.y); ev[2] = f.x; ev[3] = f.y;
                f = up2_(raw.z); ev[4] = f.x; ev[5] = f.y;
                f = up2_(raw.w); ev[6] = f.x; ev[7] = f.y;
            }
            int s   = packed & SMASK;
            int gid = ((unsigned)packed) >> 24;
            uint4 praw = pproj[s];          // 16B gather from 3.2 MB L2-resident table
            const float4* ghp = (const float4*)(ghe + gid * 8);
            float4 gh0 = ghp[0], gh1 = ghp[1];
            float acc[8];
            {
                float2 f;
                f = up2_(praw.x); acc[0] = gh0.x + f.x; acc[1] = gh0.y + f.y;
                f = up2_(praw.y); acc[2] = gh0.z + f.x; acc[3] = gh0.w + f.y;
                f = up2_(praw.z); acc[4] = gh1.x + f.x; acc[5] = gh1.y + f.y;
                f = up2_(praw.w); acc[6] = gh1.z + f.x; acc[7] = gh1.w + f.y;
            }
#pragma unroll
            for (int k = 0; k < 8; k++) {
                const float* w = He_e + k * 8;
#pragma unroll
                for (int j = 0; j < 8; j++) acc[j] = fmaf(ev[k], w[j], acc[j]);
            }
#pragma unroll
            for (int j = 0; j < 8; j++) acc[j] = relu_(acc[j]);
            uint4 packed16;
            packed16.x = pk2_(acc[0], acc[1]);
            packed16.y = pk2_(acc[2], acc[3]);
            packed16.z = pk2_(acc[4], acc[5]);
            packed16.w = pk2_(acc[6], acc[7]);
            if (local < ECAP) ebuf[local] = packed16;
            if constexpr (MODE == 1) {
                e4[i] = packed16;
            } else {
                if (local >= ECAP) e4[i] = packed16;   // overflow fallback
            }
#pragma unroll
            for (int j = 0; j < 8; j++) atomicAdd(&bins[gid * 8 + j], acc[j]);
        }
    }
    __syncthreads();

    if constexpr (MODE != 0) {
        for (int i = t; i < NG * 8; i += 256) {
            float v = bins[i];
            if (v != 0.f) atomicAdd(&gsum_e[i], v);
        }
    }

    // ---- node phase ----
    for (int v = r0 + t; v < r1; v += 256) {
        int o0 = off[v], o1 = off[v + 1];
        float iv[8];
#pragma unroll
        for (int j = 0; j < 8; j++) iv[j] = 0.f;
#pragma unroll 1
        for (int j = o0; j < o1; j++) {
            int local = j - e0;
            uint4 raw;
            if (local < ECAP) raw = ebuf[local];
            else if constexpr (MODE == 0) raw = rec2[(size_t)j * 2];
            else raw = e4[j];
            float2 f;
            f = up2_(raw.x); iv[0] += f.x; iv[1] += f.y;
            f = up2_(raw.y); iv[2] += f.x; iv[3] += f.y;
            f = up2_(raw.z); iv[4] += f.x; iv[5] += f.y;
            f = up2_(raw.w); iv[6] += f.x; iv[7] += f.y;
        }
        float sc = 1.f / fmaxf((float)(o1 - o0), 1.f);
#pragma unroll
        for (int j = 0; j < 8; j++) iv[j] *= sc;
        float nv[16];
        {
            const float4* pn = (const float4*)(nin + (size_t)v * 16);
#pragma unroll
            for (int q = 0; q < 4; q++) {
                float4 tt = pn[q];
                nv[q * 4] = tt.x; nv[q * 4 + 1] = tt.y; nv[q * 4 + 2] = tt.z; nv[q * 4 + 3] = tt.w;
            }
        }
        int gid = node_graph[v];
        float acc[16];
        {
            const float4* gp = (const float4*)(ghn + gid * 16);
#pragma unroll
            for (int q = 0; q < 4; q++) {
                float4 tt = gp[q];
                acc[q * 4] = tt.x; acc[q * 4 + 1] = tt.y; acc[q * 4 + 2] = tt.z; acc[q * 4 + 3] = tt.w;
            }
        }
#pragma unroll
        for (int k = 0; k < 16; k++) {
            const float* w = Hn_n + k * 16;
#pragma unroll
            for (int j = 0; j < 16; j++) acc[j] = fmaf(nv[k], w[j], acc[j]);
        }
#pragma unroll
        for (int k = 0; k < 8; k++) {
            const float* w = Hn_in + k * 16;
#pragma unroll
            for (int j = 0; j < 16; j++) acc[j] = fmaf(iv[k], w[j], acc[j]);
        }
#pragma unroll
        for (int j = 0; j < 16; j++) acc[j] = relu_(acc[j]);
        float4* pn = (float4*)(nout + (size_t)v * 16);
        pn[0] = make_float4(acc[0], acc[1], acc[2], acc[3]);
        pn[1] = make_float4(acc[4], acc[5], acc[6], acc[7]);
        pn[2] = make_float4(acc[8], acc[9], acc[10], acc[11]);
        pn[3] = make_float4(acc[12], acc[13], acc[14], acc[15]);
        if constexpr (MODE == 2) {
            float ro = Rn_b[0];
#pragma unroll
            for (int k = 0; k < 16; k++) ro = fmaf(acc[k], Rn[k], ro);
            out[v] = sigmoid_(ro);
        } else {
            float pj[8];
#pragma unroll
            for (int j = 0; j < 8; j++) pj[j] = 0.f;
#pragma unroll
            for (int k = 0; k < 16; k++) {
                const float* w = He_s + k * 8;
#pragma unroll
                for (int j = 0; j < 8; j++) pj[j] = fmaf(acc[k], w[j], pj[j]);
            }
            uint4 pk;
            pk.x = pk2_(pj[0], pj[1]); pk.y = pk2_(pj[2], pj[3]);
            pk.z = pk2_(pj[4], pj[5]); pk.w = pk2_(pj[6], pj[7]);
            pproj_out[v] = pk;          // double-buffered: never the gather source of THIS kernel
        }
    }
}

// ---------------- hop: global update (+ ghe/ghn rebuild, gsum_e re-zero, final readout) ----------------
__global__ void k_g_hop(
    float* __restrict__ g, float* __restrict__ gsum_e, const float* __restrict__ gsum_n,
    const int* __restrict__ ecnt, const int* __restrict__ goff,
    const float* __restrict__ Hg_e, const float* __restrict__ Hg_n,
    const float* __restrict__ Hg_g, const float* __restrict__ Hg_b,
    const float* __restrict__ He_g, const float* __restrict__ He_b,
    const float* __restrict__ Hn_g, const float* __restrict__ Hn_b,
    float* __restrict__ ghe, float* __restrict__ ghn,
    int final_flag, const float* __restrict__ Rg, const float* __restrict__ Rg_b,
    float* __restrict__ out)
{
    int gi = threadIdx.x;
    float ce = 1.f / fmaxf((float)ecnt[gi], 1.f);
    float cn = 1.f / fmaxf((float)(goff[gi + 1] - goff[gi]), 1.f);
    float em[8], nm[16], gold[4];
#pragma unroll
    for (int k = 0; k < 8; k++) { em[k] = gsum_e[gi * 8 + k] * ce; gsum_e[gi * 8 + k] = 0.f; }
#pragma unroll
    for (int k = 0; k < 16; k++) nm[k] = gsum_n[gi * 16 + k] * cn;
    {
        float4 t = *(const float4*)(g + gi * 4);
        gold[0] = t.x; gold[1] = t.y; gold[2] = t.z; gold[3] = t.w;
    }
    float acc[4];
#pragma unroll
    for (int j = 0; j < 4; j++) acc[j] = Hg_b[j];
#pragma unroll
    for (int k = 0; k < 8; k++) {
        const float* w = Hg_e + k * 4;
#pragma unroll
        for (int j = 0; j < 4; j++) acc[j] = fmaf(em[k], w[j], acc[j]);
    }
#pragma unroll
    for (int k = 0; k < 16; k++) {
        const float* w = Hg_n + k * 4;
#pragma unroll
        for (int j = 0; j < 4; j++) acc[j] = fmaf(nm[k], w[j], acc[j]);
    }
#pragma unroll
    for (int k = 0; k < 4; k++) {
        const float* w = Hg_g + k * 4;
#pragma unroll
        for (int j = 0; j < 4; j++) acc[j] = fmaf(gold[k], w[j], acc[j]);
    }
#pragma unroll
    for (int j = 0; j < 4; j++) acc[j] = relu_(acc[j]);
    *(float4*)(g + gi * 4) = make_float4(acc[0], acc[1], acc[2], acc[3]);
    float he[8];
#pragma unroll
    for (int j = 0; j < 8; j++) he[j] = He_b[j];
#pragma unroll
    for (int k = 0; k < 4; k++)
#pragma unroll
        for (int j = 0; j < 8; j++) he[j] = fmaf(acc[k], He_g[k * 8 + j], he[j]);
#pragma unroll
    for (int j = 0; j < 8; j++) ghe[gi * 8 + j] = he[j];
    float hn[16];
#pragma unroll
    for (int j = 0; j < 16; j++) hn[j] = Hn_b[j];
#pragma unroll
    for (int k = 0; k < 4; k++)
#pragma unroll
        for (int j = 0; j < 16; j++) hn[j] = fmaf(acc[k], Hn_g[k * 16 + j], hn[j]);
#pragma unroll
    for (int j = 0; j < 16; j++) ghn[gi * 16 + j] = hn[j];
    if (final_flag) {
        float ro = Rg_b[0];
#pragma unroll
        for (int k = 0; k < 4; k++) ro = fmaf(acc[k], Rg[k], ro);
        out[NNODES + gi] = sigmoid_(ro);
    }
}

extern "C" void kernel_launch(void* const* d_in, const int* in_sizes, int n_in,
                              void* d_out, int out_size, void* d_ws, size_t ws_size,
                              hipStream_t stream) {
    const float* nodes      = (const float*)d_in[0];
    const float* edges      = (const float*)d_in[1];
    const int*   senders    = (const int*)d_in[2];
    const int*   receivers  = (const int*)d_in[3];
    const int*   node_graph = (const int*)d_in[4];
    const float* We1 = (const float*)d_in[5];
    const float* be1 = (const float*)d_in[6];
    const float* Wn1 = (const float*)d_in[7];
    const float* bn1 = (const float*)d_in[8];
    const float* We2 = (const float*)d_in[9];
    const float* be2 = (const float*)d_in[10];
    const float* Wn2 = (const float*)d_in[11];
    const float* bn2 = (const float*)d_in[12];
    const float* Wg2 = (const float*)d_in[13];
    const float* bg2 = (const float*)d_in[14];
    const float* He_e = (const float*)d_in[15];
    const float* He_s = (const float*)d_in[16];
    const float* He_g = (const float*)d_in[17];
    const float* He_b = (const float*)d_in[18];
    const float* Hn_n = (const float*)d_in[19];
    const float* Hn_in = (const float*)d_in[20];
    const float* Hn_g = (const float*)d_in[21];
    const float* Hn_b = (const float*)d_in[22];
    const float* Hg_e = (const float*)d_in[23];
    const float* Hg_n = (const float*)d_in[24];
    const float* Hg_g = (const float*)d_in[25];
    const float* Hg_b = (const float*)d_in[26];
    const float* Rn   = (const float*)d_in[27];
    const float* Rn_b = (const float*)d_in[28];
    const float* Rg   = (const float*)d_in[29];
    const float* Rg_b = (const float*)d_in[30];
    float* out = (float*)d_out;

    // ---- workspace layout (all chunks 16B-aligned) ----
    char* p = (char*)d_ws;
    uint4* rec2    = (uint4*)p;  p += (size_t)NEDGES * 32;           // 102.4 MB {e1, spack}
    uint4* e4      = (uint4*)p;  p += (size_t)NEDGES * 16;           // 51.2 MB (fp16 e2)
    int*   spack   = (int*)p;    p += (size_t)NEDGES * 4;            // 12.8 MB
    float* nbufA   = (float*)p;  p += (size_t)NNODES * 16 * 4;       // 12.8 MB
    float* nbufB   = (float*)p;  p += (size_t)NNODES * 16 * 4;       // 12.8 MB
    uint4* pprojA  = (uint4*)p;  p += (size_t)NNODES * 16;           // 3.2 MB (fp16 n@He_s)
    uint4* pprojB  = (uint4*)p;  p += (size_t)NNODES * 16;           // 3.2 MB (double buffer)
    int*   deg     = (int*)p;    p += (size_t)NNODES * 4;            // zero region start
    int*   ecnt    = (int*)p;    p += (size_t)NG * 4;
    float* gsum_e  = (float*)p;  p += (size_t)NG * 8 * 4;            // zero region end
    int*   off     = (int*)p;    p += (size_t)(NNODES + 4) * 4;
    int*   cursor  = (int*)p;    p += (size_t)NNODES * 4;
    int*   goff    = (int*)p;    p += (size_t)(NG + 4) * 4;
    int*   bsum    = (int*)p;    p += (size_t)NB1 * 4 + 8;
    int*   bpre    = (int*)p;    p += (size_t)NB1 * 4 + 8;
    int*   rstart  = (int*)p;    p += (size_t)(NB + 7) * 4;
    float* gsum_n  = (float*)p;  p += (size_t)NG * 16 * 4;
    float* g       = (float*)p;  p += (size_t)NG * 4 * 4;
    float* ghe     = (float*)p;  p += (size_t)NG * 8 * 4;
    float* ghn     = (float*)p;  p += (size_t)NG * 16 * 4;

    hipMemsetAsync(deg, 0, ((size_t)NNODES + NG + NG * 8) * 4, stream);

    // ---- CSR offsets ----
    k_deg<<<1024, 256, 0, stream>>>(receivers, deg);
    k_scan1<<<NB1, 256, 0, stream>>>(deg, bsum);
    k_scan2<<<1, 64, 0, stream>>>(bsum, bpre);
    k_scan3<<<NB1, 256, 0, stream>>>(deg, bpre, off, cursor);
    k_aux<<<(NNODES + 255) / 256, 256, 0, stream>>>(node_graph, off, goff, rstart);

    // ---- node/global encoders ----
    k_node_enc<<<(NNODES + 255) / 256, 256, 0, stream>>>(nodes, Wn1, bn1, Wn2, bn2, He_s,
                                                         nbufA, pprojA);
    k_gsum_nodes<<<NG, 256, 0, stream>>>(nbufA, goff, gsum_n);
    k_g_enc<<<1, NG, 0, stream>>>(gsum_n, goff, Wg2, bg2, He_g, He_b, Hn_g, Hn_b,
                                  g, ghe, ghn);

    // ---- perm + encode + hop-1 edge update (reads pprojA) ----
    k_perm_enc<<<2048, 256, 0, stream>>>(edges, receivers, senders, node_graph,
                                         We1, be1, We2, be2, He_e, pprojA, ghe,
                                         cursor, rec2, ecnt, gsum_e);

    // ---- hop 1 (node phase only; writes pprojB = proj(n1)) ----
    k_hop<0><<<NB, 256, 0, stream>>>(rec2, spack, off, rstart, node_graph,
                                     e4, pprojA, pprojB, nbufA, nbufB, ghe, ghn,
                                     He_e, He_s, Hn_n, Hn_in, gsum_e, Rn, Rn_b, out);
    k_gsum_nodes<<<NG, 256, 0, stream>>>(nbufB, goff, gsum_n);
    k_g_hop<<<1, NG, 0, stream>>>(g, gsum_e, gsum_n, ecnt, goff, Hg_e, Hg_n, Hg_g, Hg_b,
                                  He_g, He_b, Hn_g, Hn_b, ghe, ghn, 0, Rg, Rg_b, out);
    // ---- hop 2 (reads pprojB, writes pprojA = proj(n2)) ----
    k_hop<1><<<NB, 256, 0, stream>>>(rec2, spack, off, rstart, node_graph,
                                     e4, pprojB, pprojA, nbufB, nbufA, ghe, ghn,
                                     He_e, He_s, Hn_n, Hn_in, gsum_e, Rn, Rn_b, out);
    k_gsum_nodes<<<NG, 256, 0, stream>>>(nbufA, goff, gsum_n);
    k_g_hop<<<1, NG, 0, stream>>>(g, gsum_e, gsum_n, ecnt, goff, Hg_e, Hg_n, Hg_g, Hg_b,
                                  He_g, He_b, Hn_g, Hn_b, ghe, ghn, 0, Rg, Rg_b, out);
    // ---- hop 3 (reads pprojA; fused node readout) ----
    k_hop<2><<<NB, 256, 0, stream>>>(rec2, spack, off, rstart, node_graph,
                                     e4, pprojA, pprojB, nbufA, nbufB, ghe, ghn,
                                     He_e, He_s, Hn_n, Hn_in, gsum_e, Rn, Rn_b, out);
    k_gsum_nodes<<<NG, 256, 0, stream>>>(nbufB, goff, gsum_n);
    k_g_hop<<<1, NG, 0, stream>>>(g, gsum_e, gsum_n, ecnt, goff, Hg_e, Hg_n, Hg_g, Hg_b,
                                  He_g, He_b, Hn_g, Hn_b, ghe, ghn, 1, Rg, Rg_b, out);
}

// Round 14
// 843.134 us; speedup vs baseline: 1.0261x; 1.0261x over previous
//
#include <hip/hip_runtime.h>
#include <hip/hip_fp16.h>
#include <math.h>

#define NNODES 200000
#define NEDGES 3200000
#define NG     256
#define NB1    98                      // ceil(200000/2048) for deg scan
#define EPB    1152                    // target edges per fused-hop block
#define ECAP   1280                    // LDS edge capacity (EPB + max-degree slack)
#define NB     ((NEDGES + EPB - 1) / EPB)
#define SMASK  0x00FFFFFF

static __device__ __forceinline__ float relu_(float x) { return x > 0.f ? x : 0.f; }
static __device__ __forceinline__ float sigmoid_(float x) { return 1.f / (1.f + expf(-x)); }

static __device__ __forceinline__ unsigned pk2_(float a, float b) {
    union { __half2 h; unsigned u; } x;
    x.h = __floats2half2_rn(a, b);
    return x.u;
}
static __device__ __forceinline__ float2 up2_(unsigned u) {
    union { unsigned u; __half2 h; } x; x.u = u;
    return __half22float2(x.h);
}

// ---------------- node encoder (+ He_s projection table) ----------------
__global__ __launch_bounds__(256) void k_node_enc(
    const float* __restrict__ nodes,
    const float* __restrict__ Wn1, const float* __restrict__ bn1,
    const float* __restrict__ Wn2, const float* __restrict__ bn2,
    const float* __restrict__ He_s,
    float* __restrict__ nbuf, uint4* __restrict__ pproj)
{
    int v = blockIdx.x * 256 + threadIdx.x;
    if (v >= NNODES) return;
    float acc1[32];
#pragma unroll
    for (int j = 0; j < 32; j++) acc1[j] = bn1[j];
    const float4* xp = (const float4*)(nodes + (size_t)v * 128);
#pragma unroll 1
    for (int k4 = 0; k4 < 32; k4++) {
        float4 x = xp[k4];
        const float* w = Wn1 + k4 * 4 * 32;
#pragma unroll
        for (int j = 0; j < 32; j++) acc1[j] = fmaf(x.x, w[j], acc1[j]);
#pragma unroll
        for (int j = 0; j < 32; j++) acc1[j] = fmaf(x.y, w[32 + j], acc1[j]);
#pragma unroll
        for (int j = 0; j < 32; j++) acc1[j] = fmaf(x.z, w[64 + j], acc1[j]);
#pragma unroll
        for (int j = 0; j < 32; j++) acc1[j] = fmaf(x.w, w[96 + j], acc1[j]);
    }
#pragma unroll
    for (int j = 0; j < 32; j++) acc1[j] = relu_(acc1[j]);
    float acc2[16];
#pragma unroll
    for (int j = 0; j < 16; j++) acc2[j] = bn2[j];
#pragma unroll 1
    for (int k = 0; k < 32; k++) {
        const float* w = Wn2 + k * 16;
        float x = acc1[k];
#pragma unroll
        for (int j = 0; j < 16; j++) acc2[j] = fmaf(x, w[j], acc2[j]);
    }
#pragma unroll
    for (int j = 0; j < 16; j++) acc2[j] = relu_(acc2[j]);
    float4* o4 = (float4*)(nbuf + (size_t)v * 16);
    o4[0] = make_float4(acc2[0], acc2[1], acc2[2], acc2[3]);
    o4[1] = make_float4(acc2[4], acc2[5], acc2[6], acc2[7]);
    o4[2] = make_float4(acc2[8], acc2[9], acc2[10], acc2[11]);
    o4[3] = make_float4(acc2[12], acc2[13], acc2[14], acc2[15]);
    float pj[8];
#pragma unroll
    for (int j = 0; j < 8; j++) pj[j] = 0.f;
#pragma unroll
    for (int k = 0; k < 16; k++) {
        const float* w = He_s + k * 8;
#pragma unroll
        for (int j = 0; j < 8; j++) pj[j] = fmaf(acc2[k], w[j], pj[j]);
    }
    uint4 pk;
    pk.x = pk2_(pj[0], pj[1]); pk.y = pk2_(pj[2], pj[3]);
    pk.z = pk2_(pj[4], pj[5]); pk.w = pk2_(pj[6], pj[7]);
    pproj[v] = pk;
}

// ---------------- degree histogram over receivers ----------------
__global__ __launch_bounds__(256) void k_deg(const int* __restrict__ receivers, int* __restrict__ deg)
{
    for (int i = blockIdx.x * 256 + threadIdx.x; i < NEDGES; i += gridDim.x * 256)
        atomicAdd(&deg[receivers[i]], 1);
}

// ---------------- hierarchical exclusive scan of deg -> off, cursor ----------------
__global__ __launch_bounds__(256) void k_scan1(const int* __restrict__ deg, int* __restrict__ bsum)
{
    __shared__ int ts[256];
    int b = blockIdx.x, t = threadIdx.x;
    int base = b * 2048 + t * 8;
    int s = 0;
#pragma unroll
    for (int u = 0; u < 8; u++) { int idx = base + u; if (idx < NNODES) s += deg[idx]; }
    ts[t] = s; __syncthreads();
    for (int ofs = 128; ofs > 0; ofs >>= 1) {
        if (t < ofs) ts[t] += ts[t + ofs];
        __syncthreads();
    }
    if (t == 0) bsum[b] = ts[0];
}

__global__ void k_scan2(const int* __restrict__ bsum, int* __restrict__ bpre)
{
    if (threadIdx.x == 0) {
        int acc = 0;
        for (int i = 0; i < NB1; i++) { bpre[i] = acc; acc += bsum[i]; }
    }
}

__global__ __launch_bounds__(256) void k_scan3(const int* __restrict__ deg, const int* __restrict__ bpre,
                                               int* __restrict__ off, int* __restrict__ cursor)
{
    __shared__ int ts[256];
    int b = blockIdx.x, t = threadIdx.x;
    int base = b * 2048 + t * 8;
    int loc[8]; int s = 0;
#pragma unroll
    for (int u = 0; u < 8; u++) {
        int idx = base + u;
        int d = (idx < NNODES) ? deg[idx] : 0;
        loc[u] = d; s += d;
    }
    ts[t] = s; __syncthreads();
    for (int ofs = 1; ofs < 256; ofs <<= 1) {
        int v = (t >= ofs) ? ts[t - ofs] : 0;
        __syncthreads();
        ts[t] += v;
        __syncthreads();
    }
    int ex = ((t == 0) ? 0 : ts[t - 1]) + bpre[b];
#pragma unroll
    for (int u = 0; u < 8; u++) {
        int idx = base + u;
        if (idx < NNODES) { off[idx] = ex; cursor[idx] = ex; ex += loc[u]; }
    }
    if (b == 0 && t == 0) off[NNODES] = NEDGES;
}

// ---------------- fused permutation + edge encoder + HOP-1 edge update (2x unrolled) ----------
// Early-issued cursor atomics: the ~500cy atomic round-trip overlaps the MLP compute.
__global__ __launch_bounds__(256) void k_perm_enc(
    const float* __restrict__ edges,
    const int* __restrict__ receivers, const int* __restrict__ senders,
    const int* __restrict__ node_graph,
    const float* __restrict__ We1, const float* __restrict__ be1,
    const float* __restrict__ We2, const float* __restrict__ be2,
    const float* __restrict__ He_e,
    const uint4* __restrict__ pproj, const float* __restrict__ ghe,
    int* __restrict__ cursor, uint4* __restrict__ rec2,
    int* __restrict__ ecnt, float* __restrict__ gsum_e)
{
    __shared__ int hist[NG];
    __shared__ float bins[NG * 8];
    for (int i = threadIdx.x; i < NG; i += 256) hist[i] = 0;
    for (int i = threadIdx.x; i < NG * 8; i += 256) bins[i] = 0.f;
    __syncthreads();
    const int stride = gridDim.x * 256;
    for (int i = blockIdx.x * 256 + threadIdx.x; i < NEDGES; i += 2 * stride) {
        int i2 = i + stride;
        bool v2 = (i2 < NEDGES);
        // ---- issue position atomics FIRST: latency hides under the MLP compute below ----
        int rA = receivers[i];
        int sA = senders[i];
        int posA = atomicAdd(&cursor[rA], 1);
        int rB = 0, sB = 0, posB = 0;
        if (v2) {
            rB = receivers[i2];
            sB = senders[i2];
            posB = atomicAdd(&cursor[rB], 1);
        }
        int gidA = node_graph[sA];
        int gidB = v2 ? node_graph[sB] : 0;
        // ---- encode both edges (independent chains for MLP) ----
        float accA[8], accB[8];
        {
            float x[16];
            const float4* xp = (const float4*)(edges + (size_t)i * 16);
#pragma unroll
            for (int q = 0; q < 4; q++) {
                float4 tt = xp[q];
                x[q * 4] = tt.x; x[q * 4 + 1] = tt.y; x[q * 4 + 2] = tt.z; x[q * 4 + 3] = tt.w;
            }
            float h1[4];
#pragma unroll
            for (int j = 0; j < 4; j++) h1[j] = be1[j];
#pragma unroll
            for (int k = 0; k < 16; k++) {
                const float* w = We1 + k * 4;
#pragma unroll
                for (int j = 0; j < 4; j++) h1[j] = fmaf(x[k], w[j], h1[j]);
            }
#pragma unroll
            for (int j = 0; j < 4; j++) h1[j] = relu_(h1[j]);
            float ev[8];
#pragma unroll
            for (int j = 0; j < 8; j++) ev[j] = be2[j];
#pragma unroll
            for (int k = 0; k < 4; k++) {
                const float* w = We2 + k * 8;
#pragma unroll
                for (int j = 0; j < 8; j++) ev[j] = fmaf(h1[k], w[j], ev[j]);
            }
#pragma unroll
            for (int j = 0; j < 8; j++) ev[j] = relu_(ev[j]);
            uint4 praw = pproj[sA];
            const float4* ghp = (const float4*)(ghe + gidA * 8);
            float4 gh0 = ghp[0], gh1 = ghp[1];
            float2 f;
            f = up2_(praw.x); accA[0] = gh0.x + f.x; accA[1] = gh0.y + f.y;
            f = up2_(praw.y); accA[2] = gh0.z + f.x; accA[3] = gh0.w + f.y;
            f = up2_(praw.z); accA[4] = gh1.x + f.x; accA[5] = gh1.y + f.y;
            f = up2_(praw.w); accA[6] = gh1.z + f.x; accA[7] = gh1.w + f.y;
#pragma unroll
            for (int k = 0; k < 8; k++) {
                const float* w = He_e + k * 8;
#pragma unroll
                for (int j = 0; j < 8; j++) accA[j] = fmaf(ev[k], w[j], accA[j]);
            }
#pragma unroll
            for (int j = 0; j < 8; j++) accA[j] = relu_(accA[j]);
        }
        if (v2) {
            float x[16];
            const float4* xp = (const float4*)(edges + (size_t)i2 * 16);
#pragma unroll
            for (int q = 0; q < 4; q++) {
                float4 tt = xp[q];
                x[q * 4] = tt.x; x[q * 4 + 1] = tt.y; x[q * 4 + 2] = tt.z; x[q * 4 + 3] = tt.w;
            }
            float h1[4];
#pragma unroll
            for (int j = 0; j < 4; j++) h1[j] = be1[j];
#pragma unroll
            for (int k = 0; k < 16; k++) {
                const float* w = We1 + k * 4;
#pragma unroll
                for (int j = 0; j < 4; j++) h1[j] = fmaf(x[k], w[j], h1[j]);
            }
#pragma unroll
            for (int j = 0; j < 4; j++) h1[j] = relu_(h1[j]);
            float ev[8];
#pragma unroll
            for (int j = 0; j < 8; j++) ev[j] = be2[j];
#pragma unroll
            for (int k = 0; k < 4; k++) {
                const float* w = We2 + k * 8;
#pragma unroll
                for (int j = 0; j < 8; j++) ev[j] = fmaf(h1[k], w[j], ev[j]);
            }
#pragma unroll
            for (int j = 0; j < 8; j++) ev[j] = relu_(ev[j]);
            uint4 praw = pproj[sB];
            const float4* ghp = (const float4*)(ghe + gidB * 8);
            float4 gh0 = ghp[0], gh1 = ghp[1];
            float2 f;
            f = up2_(praw.x); accB[0] = gh0.x + f.x; accB[1] = gh0.y + f.y;
            f = up2_(praw.y); accB[2] = gh0.z + f.x; accB[3] = gh0.w + f.y;
            f = up2_(praw.z); accB[4] = gh1.x + f.x; accB[5] = gh1.y + f.y;
            f = up2_(praw.w); accB[6] = gh1.z + f.x; accB[7] = gh1.w + f.y;
#pragma unroll
            for (int k = 0; k < 8; k++) {
                const float* w = He_e + k * 8;
#pragma unroll
                for (int j = 0; j < 8; j++) accB[j] = fmaf(ev[k], w[j], accB[j]);
            }
#pragma unroll
            for (int j = 0; j < 8; j++) accB[j] = relu_(accB[j]);
        }
        // ---- scatters (pos already resolved) ----
        {
            uint4 pk;
            pk.x = pk2_(accA[0], accA[1]); pk.y = pk2_(accA[2], accA[3]);
            pk.z = pk2_(accA[4], accA[5]); pk.w = pk2_(accA[6], accA[7]);
            rec2[(size_t)posA * 2]     = pk;
            rec2[(size_t)posA * 2 + 1] = make_uint4((unsigned)(sA | (gidA << 24)), 0u, 0u, 0u);
            atomicAdd(&hist[gidA], 1);
#pragma unroll
            for (int j = 0; j < 8; j++) atomicAdd(&bins[gidA * 8 + j], accA[j]);
        }
        if (v2) {
            uint4 pk;
            pk.x = pk2_(accB[0], accB[1]); pk.y = pk2_(accB[2], accB[3]);
            pk.z = pk2_(accB[4], accB[5]); pk.w = pk2_(accB[6], accB[7]);
            rec2[(size_t)posB * 2]     = pk;
            rec2[(size_t)posB * 2 + 1] = make_uint4((unsigned)(sB | (gidB << 24)), 0u, 0u, 0u);
            atomicAdd(&hist[gidB], 1);
#pragma unroll
            for (int j = 0; j < 8; j++) atomicAdd(&bins[gidB * 8 + j], accB[j]);
        }
    }
    __syncthreads();
    for (int i = threadIdx.x; i < NG; i += 256)
        if (hist[i]) atomicAdd(&ecnt[i], hist[i]);
    for (int i = threadIdx.x; i < NG * 8; i += 256) {
        float v = bins[i];
        if (v != 0.f) atomicAdd(&gsum_e[i], v);
    }
}

// ---------------- graph start offsets + per-block receiver ranges (merged) ----------------
__global__ __launch_bounds__(256) void k_aux(const int* __restrict__ ng, const int* __restrict__ off,
                                             int* __restrict__ goff, int* __restrict__ rstart)
{
    int v = blockIdx.x * 256 + threadIdx.x;
    if (v < NNODES) {
        int a = ng[v];
        if (v == 0) { for (int g = 0; g <= a; g++) goff[g] = 0; }
        else { int b = ng[v - 1]; for (int g = b + 1; g <= a; g++) goff[g] = v; }
        if (v == NNODES - 1) { for (int g = a + 1; g <= NG; g++) goff[g] = NNODES; }
    }
    if (v <= NB) {
        if (v == NB) { rstart[NB] = NNODES; }
        else {
            int target = v * EPB;
            int lo = 0, hi = NNODES;
            while (lo < hi) { int mid = (lo + hi) >> 1; if (off[mid] >= target) hi = mid; else lo = mid + 1; }
            rstart[v] = lo;
        }
    }
}

// ---------------- per-graph node sum via contiguous ranges ----------------
__global__ __launch_bounds__(256) void k_gsum_nodes(
    const float* __restrict__ nbuf, const int* __restrict__ goff, float* __restrict__ gsum_n)
{
    __shared__ float red[256 * 16];
    int g = blockIdx.x, t = threadIdx.x;
    int s = goff[g], eN = goff[g + 1];
    float acc[16];
#pragma unroll
    for (int j = 0; j < 16; j++) acc[j] = 0.f;
    for (int v = s + t; v < eN; v += 256) {
        const float4* p = (const float4*)(nbuf + (size_t)v * 16);
#pragma unroll
        for (int q = 0; q < 4; q++) {
            float4 x = p[q];
            acc[q * 4] += x.x; acc[q * 4 + 1] += x.y; acc[q * 4 + 2] += x.z; acc[q * 4 + 3] += x.w;
        }
    }
#pragma unroll
    for (int j = 0; j < 16; j++) red[t * 16 + j] = acc[j];
    __syncthreads();
    for (int ofs = 128; ofs > 0; ofs >>= 1) {
        if (t < ofs) {
#pragma unroll
            for (int j = 0; j < 16; j++) red[t * 16 + j] += red[(t + ofs) * 16 + j];
        }
        __syncthreads();
    }
    if (t < 16) gsum_n[g * 16 + t] = red[t];
}

// ---------------- g encoder (+ per-graph folded tables ghe/ghn) ----------------
__global__ void k_g_enc(
    const float* __restrict__ gsum_n, const int* __restrict__ goff,
    const float* __restrict__ Wg2, const float* __restrict__ bg2,
    const float* __restrict__ He_g, const float* __restrict__ He_b,
    const float* __restrict__ Hn_g, const float* __restrict__ Hn_b,
    float* __restrict__ g, float* __restrict__ ghe, float* __restrict__ ghn)
{
    int gi = threadIdx.x;
    float c = 1.f / fmaxf((float)(goff[gi + 1] - goff[gi]), 1.f);
    float nm[16];
#pragma unroll
    for (int k = 0; k < 16; k++) nm[k] = gsum_n[gi * 16 + k] * c;
    float acc[4];
#pragma unroll
    for (int j = 0; j < 4; j++) acc[j] = bg2[j];
#pragma unroll
    for (int k = 0; k < 16; k++) {
        const float* w = Wg2 + k * 4;
#pragma unroll
        for (int j = 0; j < 4; j++) acc[j] = fmaf(nm[k], w[j], acc[j]);
    }
    *(float4*)(g + gi * 4) = make_float4(acc[0], acc[1], acc[2], acc[3]);
    float he[8];
#pragma unroll
    for (int j = 0; j < 8; j++) he[j] = He_b[j];
#pragma unroll
    for (int k = 0; k < 4; k++)
#pragma unroll
        for (int j = 0; j < 8; j++) he[j] = fmaf(acc[k], He_g[k * 8 + j], he[j]);
#pragma unroll
    for (int j = 0; j < 8; j++) ghe[gi * 8 + j] = he[j];
    float hn[16];
#pragma unroll
    for (int j = 0; j < 16; j++) hn[j] = Hn_b[j];
#pragma unroll
    for (int k = 0; k < 4; k++)
#pragma unroll
        for (int j = 0; j < 16; j++) hn[j] = fmaf(acc[k], Hn_g[k * 16 + j], hn[j]);
#pragma unroll
    for (int j = 0; j < 16; j++) ghn[gi * 16 + j] = hn[j];
}

// ---------------- fused hop: edge phase + node phase (LDS segments) ----
// MODE 0: load rec2 (e1 precomputed) into LDS; node phase only; writes pproj_out.
// MODE 1: read rec2 {e1,spack}, compute e2, write e4 + compact spack, bins; writes pproj_out.
// MODE 2: read e4/spack, compute e3, no writes, bins; node phase + readout.
template <int MODE>
__global__ __launch_bounds__(256) void k_hop(
    const uint4* __restrict__ rec2, int* __restrict__ spack,
    const int* __restrict__ off, const int* __restrict__ rstart,
    const int* __restrict__ node_graph,
    uint4* __restrict__ e4, const uint4* __restrict__ pproj, uint4* __restrict__ pproj_out,
    const float* __restrict__ nin, float* __restrict__ nout,
    const float* __restrict__ ghe, const float* __restrict__ ghn,
    const float* __restrict__ He_e, const float* __restrict__ He_s,
    const float* __restrict__ Hn_n, const float* __restrict__ Hn_in,
    float* __restrict__ gsum_e,
    const float* __restrict__ Rn, const float* __restrict__ Rn_b,
    float* __restrict__ out)
{
    __shared__ uint4 ebuf[ECAP];        // 20 KB fp16-packed edge values
    __shared__ float bins[NG * 8];      // 8 KB per-graph edge sums
    int t = threadIdx.x;
    if constexpr (MODE != 0) {
        for (int i = t; i < NG * 8; i += 256) bins[i] = 0.f;
    }
    __syncthreads();

    int b  = blockIdx.x;
    int r0 = rstart[b], r1 = rstart[b + 1];
    int e0 = off[r0],   e1 = off[r1];

    // ---- edge phase ----
    for (int i = e0 + t; i < e1; i += 256) {
        int local = i - e0;
        if constexpr (MODE == 0) {
            if (local < ECAP) ebuf[local] = rec2[(size_t)i * 2];
            continue;
        } else {
            int packed;
            float ev[8];
            if constexpr (MODE == 1) {
                uint4 ea = rec2[(size_t)i * 2];
                uint4 eb = rec2[(size_t)i * 2 + 1];
                packed = (int)eb.x;
                spack[i] = packed;          // compact for hop 3
                float2 f;
                f = up2_(ea.x); ev[0] = f.x; ev[1] = f.y;
                f = up2_(ea.y); ev[2] = f.x; ev[3] = f.y;
                f = up2_(ea.z); ev[4] = f.x; ev[5] = f.y;
                f = up2_(ea.w); ev[6] = f.x; ev[7] = f.y;
            } else {
                packed = spack[i];
                uint4 raw = e4[i];
                float2 f;
                f = up2_(raw.x); ev[0] = f.x; ev[1] = f.y;
                f = up2_(raw.y); ev[2] = f.x; ev[3] = f.y;
                f = up2_(raw.z); ev[4] = f.x; ev[5] = f.y;
                f = up2_(raw.w); ev[6] = f.x; ev[7] = f.y;
            }
            int s   = packed & SMASK;
            int gid = ((unsigned)packed) >> 24;
            uint4 praw = pproj[s];          // 16B gather from 3.2 MB L2-resident table
            const float4* ghp = (const float4*)(ghe + gid * 8);
            float4 gh0 = ghp[0], gh1 = ghp[1];
            float acc[8];
            {
                float2 f;
                f = up2_(praw.x); acc[0] = gh0.x + f.x; acc[1] = gh0.y + f.y;
                f = up2_(praw.y); acc[2] = gh0.z + f.x; acc[3] = gh0.w + f.y;
                f = up2_(praw.z); acc[4] = gh1.x + f.x; acc[5] = gh1.y + f.y;
                f = up2_(praw.w); acc[6] = gh1.z + f.x; acc[7] = gh1.w + f.y;
            }
#pragma unroll
            for (int k = 0; k < 8; k++) {
                const float* w = He_e + k * 8;
#pragma unroll
                for (int j = 0; j < 8; j++) acc[j] = fmaf(ev[k], w[j], acc[j]);
            }
#pragma unroll
            for (int j = 0; j < 8; j++) acc[j] = relu_(acc[j]);
            uint4 packed16;
            packed16.x = pk2_(acc[0], acc[1]);
            packed16.y = pk2_(acc[2], acc[3]);
            packed16.z = pk2_(acc[4], acc[5]);
            packed16.w = pk2_(acc[6], acc[7]);
            if (local < ECAP) ebuf[local] = packed16;
            if constexpr (MODE == 1) {
                e4[i] = packed16;
            } else {
                if (local >= ECAP) e4[i] = packed16;   // overflow fallback
            }
#pragma unroll
            for (int j = 0; j < 8; j++) atomicAdd(&bins[gid * 8 + j], acc[j]);
        }
    }
    __syncthreads();

    if constexpr (MODE != 0) {
        for (int i = t; i < NG * 8; i += 256) {
            float v = bins[i];
            if (v != 0.f) atomicAdd(&gsum_e[i], v);
        }
    }

    // ---- node phase ----
    for (int v = r0 + t; v < r1; v += 256) {
        int o0 = off[v], o1 = off[v + 1];
        float iv[8];
#pragma unroll
        for (int j = 0; j < 8; j++) iv[j] = 0.f;
#pragma unroll 1
        for (int j = o0; j < o1; j++) {
            int local = j - e0;
            uint4 raw;
            if (local < ECAP) raw = ebuf[local];
            else if constexpr (MODE == 0) raw = rec2[(size_t)j * 2];
            else raw = e4[j];
            float2 f;
            f = up2_(raw.x); iv[0] += f.x; iv[1] += f.y;
            f = up2_(raw.y); iv[2] += f.x; iv[3] += f.y;
            f = up2_(raw.z); iv[4] += f.x; iv[5] += f.y;
            f = up2_(raw.w); iv[6] += f.x; iv[7] += f.y;
        }
        float sc = 1.f / fmaxf((float)(o1 - o0), 1.f);
#pragma unroll
        for (int j = 0; j < 8; j++) iv[j] *= sc;
        float nv[16];
        {
            const float4* pn = (const float4*)(nin + (size_t)v * 16);
#pragma unroll
            for (int q = 0; q < 4; q++) {
                float4 tt = pn[q];
                nv[q * 4] = tt.x; nv[q * 4 + 1] = tt.y; nv[q * 4 + 2] = tt.z; nv[q * 4 + 3] = tt.w;
            }
        }
        int gid = node_graph[v];
        float acc[16];
        {
            const float4* gp = (const float4*)(ghn + gid * 16);
#pragma unroll
            for (int q = 0; q < 4; q++) {
                float4 tt = gp[q];
                acc[q * 4] = tt.x; acc[q * 4 + 1] = tt.y; acc[q * 4 + 2] = tt.z; acc[q * 4 + 3] = tt.w;
            }
        }
#pragma unroll
        for (int k = 0; k < 16; k++) {
            const float* w = Hn_n + k * 16;
#pragma unroll
            for (int j = 0; j < 16; j++) acc[j] = fmaf(nv[k], w[j], acc[j]);
        }
#pragma unroll
        for (int k = 0; k < 8; k++) {
            const float* w = Hn_in + k * 16;
#pragma unroll
            for (int j = 0; j < 16; j++) acc[j] = fmaf(iv[k], w[j], acc[j]);
        }
#pragma unroll
        for (int j = 0; j < 16; j++) acc[j] = relu_(acc[j]);
        float4* pn = (float4*)(nout + (size_t)v * 16);
        pn[0] = make_float4(acc[0], acc[1], acc[2], acc[3]);
        pn[1] = make_float4(acc[4], acc[5], acc[6], acc[7]);
        pn[2] = make_float4(acc[8], acc[9], acc[10], acc[11]);
        pn[3] = make_float4(acc[12], acc[13], acc[14], acc[15]);
        if constexpr (MODE == 2) {
            float ro = Rn_b[0];
#pragma unroll
            for (int k = 0; k < 16; k++) ro = fmaf(acc[k], Rn[k], ro);
            out[v] = sigmoid_(ro);
        } else {
            float pj[8];
#pragma unroll
            for (int j = 0; j < 8; j++) pj[j] = 0.f;
#pragma unroll
            for (int k = 0; k < 16; k++) {
                const float* w = He_s + k * 8;
#pragma unroll
                for (int j = 0; j < 8; j++) pj[j] = fmaf(acc[k], w[j], pj[j]);
            }
            uint4 pk;
            pk.x = pk2_(pj[0], pj[1]); pk.y = pk2_(pj[2], pj[3]);
            pk.z = pk2_(pj[4], pj[5]); pk.w = pk2_(pj[6], pj[7]);
            pproj_out[v] = pk;          // double-buffered: never the gather source of THIS kernel
        }
    }
}

// ---------------- hop: global update (+ ghe/ghn rebuild, gsum_e re-zero, final readout) ----------------
__global__ void k_g_hop(
    float* __restrict__ g, float* __restrict__ gsum_e, const float* __restrict__ gsum_n,
    const int* __restrict__ ecnt, const int* __restrict__ goff,
    const float* __restrict__ Hg_e, const float* __restrict__ Hg_n,
    const float* __restrict__ Hg_g, const float* __restrict__ Hg_b,
    const float* __restrict__ He_g, const float* __restrict__ He_b,
    const float* __restrict__ Hn_g, const float* __restrict__ Hn_b,
    float* __restrict__ ghe, float* __restrict__ ghn,
    int final_flag, const float* __restrict__ Rg, const float* __restrict__ Rg_b,
    float* __restrict__ out)
{
    int gi = threadIdx.x;
    float ce = 1.f / fmaxf((float)ecnt[gi], 1.f);
    float cn = 1.f / fmaxf((float)(goff[gi + 1] - goff[gi]), 1.f);
    float em[8], nm[16], gold[4];
#pragma unroll
    for (int k = 0; k < 8; k++) { em[k] = gsum_e[gi * 8 + k] * ce; gsum_e[gi * 8 + k] = 0.f; }
#pragma unroll
    for (int k = 0; k < 16; k++) nm[k] = gsum_n[gi * 16 + k] * cn;
    {
        float4 t = *(const float4*)(g + gi * 4);
        gold[0] = t.x; gold[1] = t.y; gold[2] = t.z; gold[3] = t.w;
    }
    float acc[4];
#pragma unroll
    for (int j = 0; j < 4; j++) acc[j] = Hg_b[j];
#pragma unroll
    for (int k = 0; k < 8; k++) {
        const float* w = Hg_e + k * 4;
#pragma unroll
        for (int j = 0; j < 4; j++) acc[j] = fmaf(em[k], w[j], acc[j]);
    }
#pragma unroll
    for (int k = 0; k < 16; k++) {
        const float* w = Hg_n + k * 4;
#pragma unroll
        for (int j = 0; j < 4; j++) acc[j] = fmaf(nm[k], w[j], acc[j]);
    }
#pragma unroll
    for (int k = 0; k < 4; k++) {
        const float* w = Hg_g + k * 4;
#pragma unroll
        for (int j = 0; j < 4; j++) acc[j] = fmaf(gold[k], w[j], acc[j]);
    }
#pragma unroll
    for (int j = 0; j < 4; j++) acc[j] = relu_(acc[j]);
    *(float4*)(g + gi * 4) = make_float4(acc[0], acc[1], acc[2], acc[3]);
    float he[8];
#pragma unroll
    for (int j = 0; j < 8; j++) he[j] = He_b[j];
#pragma unroll
    for (int k = 0; k < 4; k++)
#pragma unroll
        for (int j = 0; j < 8; j++) he[j] = fmaf(acc[k], He_g[k * 8 + j], he[j]);
#pragma unroll
    for (int j = 0; j < 8; j++) ghe[gi * 8 + j] = he[j];
    float hn[16];
#pragma unroll
    for (int j = 0; j < 16; j++) hn[j] = Hn_b[j];
#pragma unroll
    for (int k = 0; k < 4; k++)
#pragma unroll
        for (int j = 0; j < 16; j++) hn[j] = fmaf(acc[k], Hn_g[k * 16 + j], hn[j]);
#pragma unroll
    for (int j = 0; j < 16; j++) ghn[gi * 16 + j] = hn[j];
    if (final_flag) {
        float ro = Rg_b[0];
#pragma unroll
        for (int k = 0; k < 4; k++) ro = fmaf(acc[k], Rg[k], ro);
        out[NNODES + gi] = sigmoid_(ro);
    }
}

extern "C" void kernel_launch(void* const* d_in, const int* in_sizes, int n_in,
                              void* d_out, int out_size, void* d_ws, size_t ws_size,
                              hipStream_t stream) {
    const float* nodes      = (const float*)d_in[0];
    const float* edges      = (const float*)d_in[1];
    const int*   senders    = (const int*)d_in[2];
    const int*   receivers  = (const int*)d_in[3];
    const int*   node_graph = (const int*)d_in[4];
    const float* We1 = (const float*)d_in[5];
    const float* be1 = (const float*)d_in[6];
    const float* Wn1 = (const float*)d_in[7];
    const float* bn1 = (const float*)d_in[8];
    const float* We2 = (const float*)d_in[9];
    const float* be2 = (const float*)d_in[10];
    const float* Wn2 = (const float*)d_in[11];
    const float* bn2 = (const float*)d_in[12];
    const float* Wg2 = (const float*)d_in[13];
    const float* bg2 = (const float*)d_in[14];
    const float* He_e = (const float*)d_in[15];
    const float* He_s = (const float*)d_in[16];
    const float* He_g = (const float*)d_in[17];
    const float* He_b = (const float*)d_in[18];
    const float* Hn_n = (const float*)d_in[19];
    const float* Hn_in = (const float*)d_in[20];
    const float* Hn_g = (const float*)d_in[21];
    const float* Hn_b = (const float*)d_in[22];
    const float* Hg_e = (const float*)d_in[23];
    const float* Hg_n = (const float*)d_in[24];
    const float* Hg_g = (const float*)d_in[25];
    const float* Hg_b = (const float*)d_in[26];
    const float* Rn   = (const float*)d_in[27];
    const float* Rn_b = (const float*)d_in[28];
    const float* Rg   = (const float*)d_in[29];
    const float* Rg_b = (const float*)d_in[30];
    float* out = (float*)d_out;

    // ---- workspace layout (all chunks 16B-aligned) ----
    char* p = (char*)d_ws;
    uint4* rec2    = (uint4*)p;  p += (size_t)NEDGES * 32;           // 102.4 MB {e1, spack}
    uint4* e4      = (uint4*)p;  p += (size_t)NEDGES * 16;           // 51.2 MB (fp16 e2)
    int*   spack   = (int*)p;    p += (size_t)NEDGES * 4;            // 12.8 MB
    float* nbufA   = (float*)p;  p += (size_t)NNODES * 16 * 4;       // 12.8 MB
    float* nbufB   = (float*)p;  p += (size_t)NNODES * 16 * 4;       // 12.8 MB
    uint4* pprojA  = (uint4*)p;  p += (size_t)NNODES * 16;           // 3.2 MB (fp16 n@He_s)
    uint4* pprojB  = (uint4*)p;  p += (size_t)NNODES * 16;           // 3.2 MB (double buffer)
    int*   deg     = (int*)p;    p += (size_t)NNODES * 4;            // zero region start
    int*   ecnt    = (int*)p;    p += (size_t)NG * 4;
    float* gsum_e  = (float*)p;  p += (size_t)NG * 8 * 4;            // zero region end
    int*   off     = (int*)p;    p += (size_t)(NNODES + 4) * 4;
    int*   cursor  = (int*)p;    p += (size_t)NNODES * 4;
    int*   goff    = (int*)p;    p += (size_t)(NG + 4) * 4;
    int*   bsum    = (int*)p;    p += (size_t)NB1 * 4 + 8;
    int*   bpre    = (int*)p;    p += (size_t)NB1 * 4 + 8;
    int*   rstart  = (int*)p;    p += (size_t)(NB + 7) * 4;
    float* gsum_n  = (float*)p;  p += (size_t)NG * 16 * 4;
    float* g       = (float*)p;  p += (size_t)NG * 4 * 4;
    float* ghe     = (float*)p;  p += (size_t)NG * 8 * 4;
    float* ghn     = (float*)p;  p += (size_t)NG * 16 * 4;

    hipMemsetAsync(deg, 0, ((size_t)NNODES + NG + NG * 8) * 4, stream);

    // ---- CSR offsets ----
    k_deg<<<1024, 256, 0, stream>>>(receivers, deg);
    k_scan1<<<NB1, 256, 0, stream>>>(deg, bsum);
    k_scan2<<<1, 64, 0, stream>>>(bsum, bpre);
    k_scan3<<<NB1, 256, 0, stream>>>(deg, bpre, off, cursor);
    k_aux<<<(NNODES + 255) / 256, 256, 0, stream>>>(node_graph, off, goff, rstart);

    // ---- node/global encoders ----
    k_node_enc<<<(NNODES + 255) / 256, 256, 0, stream>>>(nodes, Wn1, bn1, Wn2, bn2, He_s,
                                                         nbufA, pprojA);
    k_gsum_nodes<<<NG, 256, 0, stream>>>(nbufA, goff, gsum_n);
    k_g_enc<<<1, NG, 0, stream>>>(gsum_n, goff, Wg2, bg2, He_g, He_b, Hn_g, Hn_b,
                                  g, ghe, ghn);

    // ---- perm + encode + hop-1 edge update (reads pprojA) ----
    k_perm_enc<<<1024, 256, 0, stream>>>(edges, receivers, senders, node_graph,
                                         We1, be1, We2, be2, He_e, pprojA, ghe,
                                         cursor, rec2, ecnt, gsum_e);

    // ---- hop 1 (node phase only; writes pprojB = proj(n1)) ----
    k_hop<0><<<NB, 256, 0, stream>>>(rec2, spack, off, rstart, node_graph,
                                     e4, pprojA, pprojB, nbufA, nbufB, ghe, ghn,
                                     He_e, He_s, Hn_n, Hn_in, gsum_e, Rn, Rn_b, out);
    k_gsum_nodes<<<NG, 256, 0, stream>>>(nbufB, goff, gsum_n);
    k_g_hop<<<1, NG, 0, stream>>>(g, gsum_e, gsum_n, ecnt, goff, Hg_e, Hg_n, Hg_g, Hg_b,
                                  He_g, He_b, Hn_g, Hn_b, ghe, ghn, 0, Rg, Rg_b, out);
    // ---- hop 2 (reads pprojB, writes pprojA = proj(n2)) ----
    k_hop<1><<<NB, 256, 0, stream>>>(rec2, spack, off, rstart, node_graph,
                                     e4, pprojB, pprojA, nbufB, nbufA, ghe, ghn,
                                     He_e, He_s, Hn_n, Hn_in, gsum_e, Rn, Rn_b, out);
    k_gsum_nodes<<<NG, 256, 0, stream>>>(nbufA, goff, gsum_n);
    k_g_hop<<<1, NG, 0, stream>>>(g, gsum_e, gsum_n, ecnt, goff, Hg_e, Hg_n, Hg_g, Hg_b,
                                  He_g, He_b, Hn_g, Hn_b, ghe, ghn, 0, Rg, Rg_b, out);
    // ---- hop 3 (reads pprojA; fused node readout) ----
    k_hop<2><<<NB, 256, 0, stream>>>(rec2, spack, off, rstart, node_graph,
                                     e4, pprojA, pprojB, nbufA, nbufB, ghe, ghn,
                                     He_e, He_s, Hn_n, Hn_in, gsum_e, Rn, Rn_b, out);
    k_gsum_nodes<<<NG, 256, 0, stream>>>(nbufB, goff, gsum_n);
    k_g_hop<<<1, NG, 0, stream>>>(g, gsum_e, gsum_n, ecnt, goff, Hg_e, Hg_n, Hg_g, Hg_b,
                                  He_g, He_b, Hn_g, Hn_b, ghe, ghn, 1, Rg, Rg_b, out);
}

// Round 15
// 831.272 us; speedup vs baseline: 1.0407x; 1.0143x over previous
//
#include <hip/hip_runtime.h>
#include <hip/hip_fp16.h>
#include <math.h>

#define NNODES 200000
#define NEDGES 3200000
#define NG     256
#define NB1    98                      // ceil(200000/2048) for deg scan
#define EPB    1152                    // target edges per fused-hop block
#define ECAP   1280                    // LDS edge capacity (EPB + max-degree slack)
#define NB     ((NEDGES + EPB - 1) / EPB)
#define SMASK  0x00FFFFFF

static __device__ __forceinline__ float relu_(float x) { return x > 0.f ? x : 0.f; }
static __device__ __forceinline__ float sigmoid_(float x) { return 1.f / (1.f + expf(-x)); }

static __device__ __forceinline__ unsigned pk2_(float a, float b) {
    union { __half2 h; unsigned u; } x;
    x.h = __floats2half2_rn(a, b);
    return x.u;
}
static __device__ __forceinline__ float2 up2_(unsigned u) {
    union { unsigned u; __half2 h; } x; x.u = u;
    return __half22float2(x.h);
}

// ---------------- node encoder (+ He_s projection table) ----------------
__global__ __launch_bounds__(256) void k_node_enc(
    const float* __restrict__ nodes,
    const float* __restrict__ Wn1, const float* __restrict__ bn1,
    const float* __restrict__ Wn2, const float* __restrict__ bn2,
    const float* __restrict__ He_s,
    float* __restrict__ nbuf, uint4* __restrict__ pproj)
{
    int v = blockIdx.x * 256 + threadIdx.x;
    if (v >= NNODES) return;
    float acc1[32];
#pragma unroll
    for (int j = 0; j < 32; j++) acc1[j] = bn1[j];
    const float4* xp = (const float4*)(nodes + (size_t)v * 128);
#pragma unroll 1
    for (int k4 = 0; k4 < 32; k4++) {
        float4 x = xp[k4];
        const float* w = Wn1 + k4 * 4 * 32;
#pragma unroll
        for (int j = 0; j < 32; j++) acc1[j] = fmaf(x.x, w[j], acc1[j]);
#pragma unroll
        for (int j = 0; j < 32; j++) acc1[j] = fmaf(x.y, w[32 + j], acc1[j]);
#pragma unroll
        for (int j = 0; j < 32; j++) acc1[j] = fmaf(x.z, w[64 + j], acc1[j]);
#pragma unroll
        for (int j = 0; j < 32; j++) acc1[j] = fmaf(x.w, w[96 + j], acc1[j]);
    }
#pragma unroll
    for (int j = 0; j < 32; j++) acc1[j] = relu_(acc1[j]);
    float acc2[16];
#pragma unroll
    for (int j = 0; j < 16; j++) acc2[j] = bn2[j];
#pragma unroll 1
    for (int k = 0; k < 32; k++) {
        const float* w = Wn2 + k * 16;
        float x = acc1[k];
#pragma unroll
        for (int j = 0; j < 16; j++) acc2[j] = fmaf(x, w[j], acc2[j]);
    }
#pragma unroll
    for (int j = 0; j < 16; j++) acc2[j] = relu_(acc2[j]);
    float4* o4 = (float4*)(nbuf + (size_t)v * 16);
    o4[0] = make_float4(acc2[0], acc2[1], acc2[2], acc2[3]);
    o4[1] = make_float4(acc2[4], acc2[5], acc2[6], acc2[7]);
    o4[2] = make_float4(acc2[8], acc2[9], acc2[10], acc2[11]);
    o4[3] = make_float4(acc2[12], acc2[13], acc2[14], acc2[15]);
    float pj[8];
#pragma unroll
    for (int j = 0; j < 8; j++) pj[j] = 0.f;
#pragma unroll
    for (int k = 0; k < 16; k++) {
        const float* w = He_s + k * 8;
#pragma unroll
        for (int j = 0; j < 8; j++) pj[j] = fmaf(acc2[k], w[j], pj[j]);
    }
    uint4 pk;
    pk.x = pk2_(pj[0], pj[1]); pk.y = pk2_(pj[2], pj[3]);
    pk.z = pk2_(pj[4], pj[5]); pk.w = pk2_(pj[6], pj[7]);
    pproj[v] = pk;
}

// ---------------- degree histogram over receivers ----------------
__global__ __launch_bounds__(256) void k_deg(const int* __restrict__ receivers, int* __restrict__ deg)
{
    for (int i = blockIdx.x * 256 + threadIdx.x; i < NEDGES; i += gridDim.x * 256)
        atomicAdd(&deg[receivers[i]], 1);
}

// ---------------- hierarchical exclusive scan of deg -> off, cursor ----------------
__global__ __launch_bounds__(256) void k_scan1(const int* __restrict__ deg, int* __restrict__ bsum)
{
    __shared__ int ts[256];
    int b = blockIdx.x, t = threadIdx.x;
    int base = b * 2048 + t * 8;
    int s = 0;
#pragma unroll
    for (int u = 0; u < 8; u++) { int idx = base + u; if (idx < NNODES) s += deg[idx]; }
    ts[t] = s; __syncthreads();
    for (int ofs = 128; ofs > 0; ofs >>= 1) {
        if (t < ofs) ts[t] += ts[t + ofs];
        __syncthreads();
    }
    if (t == 0) bsum[b] = ts[0];
}

__global__ void k_scan2(const int* __restrict__ bsum, int* __restrict__ bpre)
{
    if (threadIdx.x == 0) {
        int acc = 0;
        for (int i = 0; i < NB1; i++) { bpre[i] = acc; acc += bsum[i]; }
    }
}

__global__ __launch_bounds__(256) void k_scan3(const int* __restrict__ deg, const int* __restrict__ bpre,
                                               int* __restrict__ off, int* __restrict__ cursor)
{
    __shared__ int ts[256];
    int b = blockIdx.x, t = threadIdx.x;
    int base = b * 2048 + t * 8;
    int loc[8]; int s = 0;
#pragma unroll
    for (int u = 0; u < 8; u++) {
        int idx = base + u;
        int d = (idx < NNODES) ? deg[idx] : 0;
        loc[u] = d; s += d;
    }
    ts[t] = s; __syncthreads();
    for (int ofs = 1; ofs < 256; ofs <<= 1) {
        int v = (t >= ofs) ? ts[t - ofs] : 0;
        __syncthreads();
        ts[t] += v;
        __syncthreads();
    }
    int ex = ((t == 0) ? 0 : ts[t - 1]) + bpre[b];
#pragma unroll
    for (int u = 0; u < 8; u++) {
        int idx = base + u;
        if (idx < NNODES) { off[idx] = ex; cursor[idx] = ex; ex += loc[u]; }
    }
    if (b == 0 && t == 0) off[NNODES] = NEDGES;
}

// ---------------- fused permutation + edge encoder + HOP-1 edge update (2x unrolled) ----------
// R12 ordering restored: compute first, cursor atomic after (loads prefetch across iterations).
__global__ __launch_bounds__(256) void k_perm_enc(
    const float* __restrict__ edges,
    const int* __restrict__ receivers, const int* __restrict__ senders,
    const int* __restrict__ node_graph,
    const float* __restrict__ We1, const float* __restrict__ be1,
    const float* __restrict__ We2, const float* __restrict__ be2,
    const float* __restrict__ He_e,
    const uint4* __restrict__ pproj, const float* __restrict__ ghe,
    int* __restrict__ cursor, uint4* __restrict__ rec2,
    int* __restrict__ ecnt, float* __restrict__ gsum_e)
{
    __shared__ int hist[NG];
    __shared__ float bins[NG * 8];
    for (int i = threadIdx.x; i < NG; i += 256) hist[i] = 0;
    for (int i = threadIdx.x; i < NG * 8; i += 256) bins[i] = 0.f;
    __syncthreads();
    const int stride = gridDim.x * 256;
    for (int i = blockIdx.x * 256 + threadIdx.x; i < NEDGES; i += 2 * stride) {
        int i2 = i + stride;
        bool v2 = (i2 < NEDGES);
        float accA[8], accB[8];
        int rA = 0, sA = 0, gidA = 0, rB = 0, sB = 0, gidB = 0;
        {
            float x[16];
            const float4* xp = (const float4*)(edges + (size_t)i * 16);
#pragma unroll
            for (int q = 0; q < 4; q++) {
                float4 tt = xp[q];
                x[q * 4] = tt.x; x[q * 4 + 1] = tt.y; x[q * 4 + 2] = tt.z; x[q * 4 + 3] = tt.w;
            }
            float h1[4];
#pragma unroll
            for (int j = 0; j < 4; j++) h1[j] = be1[j];
#pragma unroll
            for (int k = 0; k < 16; k++) {
                const float* w = We1 + k * 4;
#pragma unroll
                for (int j = 0; j < 4; j++) h1[j] = fmaf(x[k], w[j], h1[j]);
            }
#pragma unroll
            for (int j = 0; j < 4; j++) h1[j] = relu_(h1[j]);
            float ev[8];
#pragma unroll
            for (int j = 0; j < 8; j++) ev[j] = be2[j];
#pragma unroll
            for (int k = 0; k < 4; k++) {
                const float* w = We2 + k * 8;
#pragma unroll
                for (int j = 0; j < 8; j++) ev[j] = fmaf(h1[k], w[j], ev[j]);
            }
#pragma unroll
            for (int j = 0; j < 8; j++) ev[j] = relu_(ev[j]);
            rA = receivers[i]; sA = senders[i]; gidA = node_graph[sA];
            uint4 praw = pproj[sA];
            const float4* ghp = (const float4*)(ghe + gidA * 8);
            float4 gh0 = ghp[0], gh1 = ghp[1];
            float2 f;
            f = up2_(praw.x); accA[0] = gh0.x + f.x; accA[1] = gh0.y + f.y;
            f = up2_(praw.y); accA[2] = gh0.z + f.x; accA[3] = gh0.w + f.y;
            f = up2_(praw.z); accA[4] = gh1.x + f.x; accA[5] = gh1.y + f.y;
            f = up2_(praw.w); accA[6] = gh1.z + f.x; accA[7] = gh1.w + f.y;
#pragma unroll
            for (int k = 0; k < 8; k++) {
                const float* w = He_e + k * 8;
#pragma unroll
                for (int j = 0; j < 8; j++) accA[j] = fmaf(ev[k], w[j], accA[j]);
            }
#pragma unroll
            for (int j = 0; j < 8; j++) accA[j] = relu_(accA[j]);
        }
        if (v2) {
            float x[16];
            const float4* xp = (const float4*)(edges + (size_t)i2 * 16);
#pragma unroll
            for (int q = 0; q < 4; q++) {
                float4 tt = xp[q];
                x[q * 4] = tt.x; x[q * 4 + 1] = tt.y; x[q * 4 + 2] = tt.z; x[q * 4 + 3] = tt.w;
            }
            float h1[4];
#pragma unroll
            for (int j = 0; j < 4; j++) h1[j] = be1[j];
#pragma unroll
            for (int k = 0; k < 16; k++) {
                const float* w = We1 + k * 4;
#pragma unroll
                for (int j = 0; j < 4; j++) h1[j] = fmaf(x[k], w[j], h1[j]);
            }
#pragma unroll
            for (int j = 0; j < 4; j++) h1[j] = relu_(h1[j]);
            float ev[8];
#pragma unroll
            for (int j = 0; j < 8; j++) ev[j] = be2[j];
#pragma unroll
            for (int k = 0; k < 4; k++) {
                const float* w = We2 + k * 8;
#pragma unroll
                for (int j = 0; j < 8; j++) ev[j] = fmaf(h1[k], w[j], ev[j]);
            }
#pragma unroll
            for (int j = 0; j < 8; j++) ev[j] = relu_(ev[j]);
            rB = receivers[i2]; sB = senders[i2]; gidB = node_graph[sB];
            uint4 praw = pproj[sB];
            const float4* ghp = (const float4*)(ghe + gidB * 8);
            float4 gh0 = ghp[0], gh1 = ghp[1];
            float2 f;
            f = up2_(praw.x); accB[0] = gh0.x + f.x; accB[1] = gh0.y + f.y;
            f = up2_(praw.y); accB[2] = gh0.z + f.x; accB[3] = gh0.w + f.y;
            f = up2_(praw.z); accB[4] = gh1.x + f.x; accB[5] = gh1.y + f.y;
            f = up2_(praw.w); accB[6] = gh1.z + f.x; accB[7] = gh1.w + f.y;
#pragma unroll
            for (int k = 0; k < 8; k++) {
                const float* w = He_e + k * 8;
#pragma unroll
                for (int j = 0; j < 8; j++) accB[j] = fmaf(ev[k], w[j], accB[j]);
            }
#pragma unroll
            for (int j = 0; j < 8; j++) accB[j] = relu_(accB[j]);
        }
        int posA = atomicAdd(&cursor[rA], 1);
        int posB = v2 ? atomicAdd(&cursor[rB], 1) : 0;
        {
            uint4 pk;
            pk.x = pk2_(accA[0], accA[1]); pk.y = pk2_(accA[2], accA[3]);
            pk.z = pk2_(accA[4], accA[5]); pk.w = pk2_(accA[6], accA[7]);
            rec2[(size_t)posA * 2]     = pk;
            rec2[(size_t)posA * 2 + 1] = make_uint4((unsigned)(sA | (gidA << 24)), 0u, 0u, 0u);
            atomicAdd(&hist[gidA], 1);
#pragma unroll
            for (int j = 0; j < 8; j++) atomicAdd(&bins[gidA * 8 + j], accA[j]);
        }
        if (v2) {
            uint4 pk;
            pk.x = pk2_(accB[0], accB[1]); pk.y = pk2_(accB[2], accB[3]);
            pk.z = pk2_(accB[4], accB[5]); pk.w = pk2_(accB[6], accB[7]);
            rec2[(size_t)posB * 2]     = pk;
            rec2[(size_t)posB * 2 + 1] = make_uint4((unsigned)(sB | (gidB << 24)), 0u, 0u, 0u);
            atomicAdd(&hist[gidB], 1);
#pragma unroll
            for (int j = 0; j < 8; j++) atomicAdd(&bins[gidB * 8 + j], accB[j]);
        }
    }
    __syncthreads();
    for (int i = threadIdx.x; i < NG; i += 256)
        if (hist[i]) atomicAdd(&ecnt[i], hist[i]);
    for (int i = threadIdx.x; i < NG * 8; i += 256) {
        float v = bins[i];
        if (v != 0.f) atomicAdd(&gsum_e[i], v);
    }
}

// ---------------- graph start offsets + per-block receiver ranges (merged) ----------------
__global__ __launch_bounds__(256) void k_aux(const int* __restrict__ ng, const int* __restrict__ off,
                                             int* __restrict__ goff, int* __restrict__ rstart)
{
    int v = blockIdx.x * 256 + threadIdx.x;
    if (v < NNODES) {
        int a = ng[v];
        if (v == 0) { for (int g = 0; g <= a; g++) goff[g] = 0; }
        else { int b = ng[v - 1]; for (int g = b + 1; g <= a; g++) goff[g] = v; }
        if (v == NNODES - 1) { for (int g = a + 1; g <= NG; g++) goff[g] = NNODES; }
    }
    if (v <= NB) {
        if (v == NB) { rstart[NB] = NNODES; }
        else {
            int target = v * EPB;
            int lo = 0, hi = NNODES;
            while (lo < hi) { int mid = (lo + hi) >> 1; if (off[mid] >= target) hi = mid; else lo = mid + 1; }
            rstart[v] = lo;
        }
    }
}

// ---------------- per-graph node sum via contiguous ranges ----------------
__global__ __launch_bounds__(256) void k_gsum_nodes(
    const float* __restrict__ nbuf, const int* __restrict__ goff, float* __restrict__ gsum_n)
{
    __shared__ float red[256 * 16];
    int g = blockIdx.x, t = threadIdx.x;
    int s = goff[g], eN = goff[g + 1];
    float acc[16];
#pragma unroll
    for (int j = 0; j < 16; j++) acc[j] = 0.f;
    for (int v = s + t; v < eN; v += 256) {
        const float4* p = (const float4*)(nbuf + (size_t)v * 16);
#pragma unroll
        for (int q = 0; q < 4; q++) {
            float4 x = p[q];
            acc[q * 4] += x.x; acc[q * 4 + 1] += x.y; acc[q * 4 + 2] += x.z; acc[q * 4 + 3] += x.w;
        }
    }
#pragma unroll
    for (int j = 0; j < 16; j++) red[t * 16 + j] = acc[j];
    __syncthreads();
    for (int ofs = 128; ofs > 0; ofs >>= 1) {
        if (t < ofs) {
#pragma unroll
            for (int j = 0; j < 16; j++) red[t * 16 + j] += red[(t + ofs) * 16 + j];
        }
        __syncthreads();
    }
    if (t < 16) gsum_n[g * 16 + t] = red[t];
}

// ---------------- g encoder (+ per-graph folded tables ghe/ghn) ----------------
__global__ void k_g_enc(
    const float* __restrict__ gsum_n, const int* __restrict__ goff,
    const float* __restrict__ Wg2, const float* __restrict__ bg2,
    const float* __restrict__ He_g, const float* __restrict__ He_b,
    const float* __restrict__ Hn_g, const float* __restrict__ Hn_b,
    float* __restrict__ g, float* __restrict__ ghe, float* __restrict__ ghn)
{
    int gi = threadIdx.x;
    float c = 1.f / fmaxf((float)(goff[gi + 1] - goff[gi]), 1.f);
    float nm[16];
#pragma unroll
    for (int k = 0; k < 16; k++) nm[k] = gsum_n[gi * 16 + k] * c;
    float acc[4];
#pragma unroll
    for (int j = 0; j < 4; j++) acc[j] = bg2[j];
#pragma unroll
    for (int k = 0; k < 16; k++) {
        const float* w = Wg2 + k * 4;
#pragma unroll
        for (int j = 0; j < 4; j++) acc[j] = fmaf(nm[k], w[j], acc[j]);
    }
    *(float4*)(g + gi * 4) = make_float4(acc[0], acc[1], acc[2], acc[3]);
    float he[8];
#pragma unroll
    for (int j = 0; j < 8; j++) he[j] = He_b[j];
#pragma unroll
    for (int k = 0; k < 4; k++)
#pragma unroll
        for (int j = 0; j < 8; j++) he[j] = fmaf(acc[k], He_g[k * 8 + j], he[j]);
#pragma unroll
    for (int j = 0; j < 8; j++) ghe[gi * 8 + j] = he[j];
    float hn[16];
#pragma unroll
    for (int j = 0; j < 16; j++) hn[j] = Hn_b[j];
#pragma unroll
    for (int k = 0; k < 4; k++)
#pragma unroll
        for (int j = 0; j < 16; j++) hn[j] = fmaf(acc[k], Hn_g[k * 16 + j], hn[j]);
#pragma unroll
    for (int j = 0; j < 16; j++) ghn[gi * 16 + j] = hn[j];
}

// ---------------- fused hop: edge phase + node phase (LDS segments) ----
// MODE 0: load rec2 (e1 precomputed) into LDS; node phase only; writes pproj_out.
// MODE 1: read rec2 {e1,spack}, compute e2, write e4 + compact spack, bins; writes pproj_out.
// MODE 2: read e4/spack, compute e3, no writes, bins; node phase + readout.
template <int MODE>
__global__ __launch_bounds__(256) void k_hop(
    const uint4* __restrict__ rec2, int* __restrict__ spack,
    const int* __restrict__ off, const int* __restrict__ rstart,
    const int* __restrict__ node_graph,
    uint4* __restrict__ e4, const uint4* __restrict__ pproj, uint4* __restrict__ pproj_out,
    const float* __restrict__ nin, float* __restrict__ nout,
    const float* __restrict__ ghe, const float* __restrict__ ghn,
    const float* __restrict__ He_e, const float* __restrict__ He_s,
    const float* __restrict__ Hn_n, const float* __restrict__ Hn_in,
    float* __restrict__ gsum_e,
    const float* __restrict__ Rn, const float* __restrict__ Rn_b,
    float* __restrict__ out)
{
    __shared__ uint4 ebuf[ECAP];        // 20 KB fp16-packed edge values
    __shared__ float bins[NG * 8];      // 8 KB per-graph edge sums
    int t = threadIdx.x;
    if constexpr (MODE != 0) {
        for (int i = t; i < NG * 8; i += 256) bins[i] = 0.f;
    }
    __syncthreads();

    int b  = blockIdx.x;
    int r0 = rstart[b], r1 = rstart[b + 1];
    int e0 = off[r0],   e1 = off[r1];

    // ---- edge phase ----
    for (int i = e0 + t; i < e1; i += 256) {
        int local = i - e0;
        if constexpr (MODE == 0) {
            if (local < ECAP) ebuf[local] = rec2[(size_t)i * 2];
            continue;
        } else {
            int packed;
            float ev[8];
            if constexpr (MODE == 1) {
                uint4 ea = rec2[(size_t)i * 2];
                uint4 eb = rec2[(size_t)i * 2 + 1];
                packed = (int)eb.x;
                spack[i] = packed;          // compact for hop 3
                float2 f;
                f = up2_(ea.x); ev[0] = f.x; ev[1] = f.y;
                f = up2_(ea.y); ev[2] = f.x; ev[3] = f.y;
                f = up2_(ea.z); ev[4] = f.x; ev[5] = f.y;
                f = up2_(ea.w); ev[6] = f.x; ev[7] = f.y;
            } else {
                packed = spack[i];
                uint4 raw = e4[i];
                float2 f;
                f = up2_(raw.x); ev[0] = f.x; ev[1] = f.y;
                f = up2_(raw.y); ev[2] = f.x; ev[3] = f.y;
                f = up2_(raw.z); ev[4] = f.x; ev[5] = f.y;
                f = up2_(raw.w); ev[6] = f.x; ev[7] = f.y;
            }
            int s   = packed & SMASK;
            int gid = ((unsigned)packed) >> 24;
            uint4 praw = pproj[s];          // 16B gather from 3.2 MB L2-resident table
            const float4* ghp = (const float4*)(ghe + gid * 8);
            float4 gh0 = ghp[0], gh1 = ghp[1];
            float acc[8];
            {
                float2 f;
                f = up2_(praw.x); acc[0] = gh0.x + f.x; acc[1] = gh0.y + f.y;
                f = up2_(praw.y); acc[2] = gh0.z + f.x; acc[3] = gh0.w + f.y;
                f = up2_(praw.z); acc[4] = gh1.x + f.x; acc[5] = gh1.y + f.y;
                f = up2_(praw.w); acc[6] = gh1.z + f.x; acc[7] = gh1.w + f.y;
            }
#pragma unroll
            for (int k = 0; k < 8; k++) {
                const float* w = He_e + k * 8;
#pragma unroll
                for (int j = 0; j < 8; j++) acc[j] = fmaf(ev[k], w[j], acc[j]);
            }
#pragma unroll
            for (int j = 0; j < 8; j++) acc[j] = relu_(acc[j]);
            uint4 packed16;
            packed16.x = pk2_(acc[0], acc[1]);
            packed16.y = pk2_(acc[2], acc[3]);
            packed16.z = pk2_(acc[4], acc[5]);
            packed16.w = pk2_(acc[6], acc[7]);
            if (local < ECAP) ebuf[local] = packed16;
            if constexpr (MODE == 1) {
                e4[i] = packed16;
            } else {
                if (local >= ECAP) e4[i] = packed16;   // overflow fallback
            }
#pragma unroll
            for (int j = 0; j < 8; j++) atomicAdd(&bins[gid * 8 + j], acc[j]);
        }
    }
    __syncthreads();

    if constexpr (MODE != 0) {
        for (int i = t; i < NG * 8; i += 256) {
            float v = bins[i];
            if (v != 0.f) atomicAdd(&gsum_e[i], v);
        }
    }

    // ---- node phase ----
    for (int v = r0 + t; v < r1; v += 256) {
        int o0 = off[v], o1 = off[v + 1];
        float iv[8];
#pragma unroll
        for (int j = 0; j < 8; j++) iv[j] = 0.f;
#pragma unroll 1
        for (int j = o0; j < o1; j++) {
            int local = j - e0;
            uint4 raw;
            if (local < ECAP) raw = ebuf[local];
            else if constexpr (MODE == 0) raw = rec2[(size_t)j * 2];
            else raw = e4[j];
            float2 f;
            f = up2_(raw.x); iv[0] += f.x; iv[1] += f.y;
            f = up2_(raw.y); iv[2] += f.x; iv[3] += f.y;
            f = up2_(raw.z); iv[4] += f.x; iv[5] += f.y;
            f = up2_(raw.w); iv[6] += f.x; iv[7] += f.y;
        }
        float sc = 1.f / fmaxf((float)(o1 - o0), 1.f);
#pragma unroll
        for (int j = 0; j < 8; j++) iv[j] *= sc;
        float nv[16];
        {
            const float4* pn = (const float4*)(nin + (size_t)v * 16);
#pragma unroll
            for (int q = 0; q < 4; q++) {
                float4 tt = pn[q];
                nv[q * 4] = tt.x; nv[q * 4 + 1] = tt.y; nv[q * 4 + 2] = tt.z; nv[q * 4 + 3] = tt.w;
            }
        }
        int gid = node_graph[v];
        float acc[16];
        {
            const float4* gp = (const float4*)(ghn + gid * 16);
#pragma unroll
            for (int q = 0; q < 4; q++) {
                float4 tt = gp[q];
                acc[q * 4] = tt.x; acc[q * 4 + 1] = tt.y; acc[q * 4 + 2] = tt.z; acc[q * 4 + 3] = tt.w;
            }
        }
#pragma unroll
        for (int k = 0; k < 16; k++) {
            const float* w = Hn_n + k * 16;
#pragma unroll
            for (int j = 0; j < 16; j++) acc[j] = fmaf(nv[k], w[j], acc[j]);
        }
#pragma unroll
        for (int k = 0; k < 8; k++) {
            const float* w = Hn_in + k * 16;
#pragma unroll
            for (int j = 0; j < 16; j++) acc[j] = fmaf(iv[k], w[j], acc[j]);
        }
#pragma unroll
        for (int j = 0; j < 16; j++) acc[j] = relu_(acc[j]);
        float4* pn = (float4*)(nout + (size_t)v * 16);
        pn[0] = make_float4(acc[0], acc[1], acc[2], acc[3]);
        pn[1] = make_float4(acc[4], acc[5], acc[6], acc[7]);
        pn[2] = make_float4(acc[8], acc[9], acc[10], acc[11]);
        pn[3] = make_float4(acc[12], acc[13], acc[14], acc[15]);
        if constexpr (MODE == 2) {
            float ro = Rn_b[0];
#pragma unroll
            for (int k = 0; k < 16; k++) ro = fmaf(acc[k], Rn[k], ro);
            out[v] = sigmoid_(ro);
        } else {
            float pj[8];
#pragma unroll
            for (int j = 0; j < 8; j++) pj[j] = 0.f;
#pragma unroll
            for (int k = 0; k < 16; k++) {
                const float* w = He_s + k * 8;
#pragma unroll
                for (int j = 0; j < 8; j++) pj[j] = fmaf(acc[k], w[j], pj[j]);
            }
            uint4 pk;
            pk.x = pk2_(pj[0], pj[1]); pk.y = pk2_(pj[2], pj[3]);
            pk.z = pk2_(pj[4], pj[5]); pk.w = pk2_(pj[6], pj[7]);
            pproj_out[v] = pk;          // double-buffered: never the gather source of THIS kernel
        }
    }
}

// ---------------- hop: global update (+ ghe/ghn rebuild, gsum_e re-zero, final readout) ----------------
__global__ void k_g_hop(
    float* __restrict__ g, float* __restrict__ gsum_e, const float* __restrict__ gsum_n,
    const int* __restrict__ ecnt, const int* __restrict__ goff,
    const float* __restrict__ Hg_e, const float* __restrict__ Hg_n,
    const float* __restrict__ Hg_g, const float* __restrict__ Hg_b,
    const float* __restrict__ He_g, const float* __restrict__ He_b,
    const float* __restrict__ Hn_g, const float* __restrict__ Hn_b,
    float* __restrict__ ghe, float* __restrict__ ghn,
    int final_flag, const float* __restrict__ Rg, const float* __restrict__ Rg_b,
    float* __restrict__ out)
{
    int gi = threadIdx.x;
    float ce = 1.f / fmaxf((float)ecnt[gi], 1.f);
    float cn = 1.f / fmaxf((float)(goff[gi + 1] - goff[gi]), 1.f);
    float em[8], nm[16], gold[4];
#pragma unroll
    for (int k = 0; k < 8; k++) { em[k] = gsum_e[gi * 8 + k] * ce; gsum_e[gi * 8 + k] = 0.f; }
#pragma unroll
    for (int k = 0; k < 16; k++) nm[k] = gsum_n[gi * 16 + k] * cn;
    {
        float4 t = *(const float4*)(g + gi * 4);
        gold[0] = t.x; gold[1] = t.y; gold[2] = t.z; gold[3] = t.w;
    }
    float acc[4];
#pragma unroll
    for (int j = 0; j < 4; j++) acc[j] = Hg_b[j];
#pragma unroll
    for (int k = 0; k < 8; k++) {
        const float* w = Hg_e + k * 4;
#pragma unroll
        for (int j = 0; j < 4; j++) acc[j] = fmaf(em[k], w[j], acc[j]);
    }
#pragma unroll
    for (int k = 0; k < 16; k++) {
        const float* w = Hg_n + k * 4;
#pragma unroll
        for (int j = 0; j < 4; j++) acc[j] = fmaf(nm[k], w[j], acc[j]);
    }
#pragma unroll
    for (int k = 0; k < 4; k++) {
        const float* w = Hg_g + k * 4;
#pragma unroll
        for (int j = 0; j < 4; j++) acc[j] = fmaf(gold[k], w[j], acc[j]);
    }
#pragma unroll
    for (int j = 0; j < 4; j++) acc[j] = relu_(acc[j]);
    *(float4*)(g + gi * 4) = make_float4(acc[0], acc[1], acc[2], acc[3]);
    float he[8];
#pragma unroll
    for (int j = 0; j < 8; j++) he[j] = He_b[j];
#pragma unroll
    for (int k = 0; k < 4; k++)
#pragma unroll
        for (int j = 0; j < 8; j++) he[j] = fmaf(acc[k], He_g[k * 8 + j], he[j]);
#pragma unroll
    for (int j = 0; j < 8; j++) ghe[gi * 8 + j] = he[j];
    float hn[16];
#pragma unroll
    for (int j = 0; j < 16; j++) hn[j] = Hn_b[j];
#pragma unroll
    for (int k = 0; k < 4; k++)
#pragma unroll
        for (int j = 0; j < 16; j++) hn[j] = fmaf(acc[k], Hn_g[k * 16 + j], hn[j]);
#pragma unroll
    for (int j = 0; j < 16; j++) ghn[gi * 16 + j] = hn[j];
    if (final_flag) {
        float ro = Rg_b[0];
#pragma unroll
        for (int k = 0; k < 4; k++) ro = fmaf(acc[k], Rg[k], ro);
        out[NNODES + gi] = sigmoid_(ro);
    }
}

extern "C" void kernel_launch(void* const* d_in, const int* in_sizes, int n_in,
                              void* d_out, int out_size, void* d_ws, size_t ws_size,
                              hipStream_t stream) {
    const float* nodes      = (const float*)d_in[0];
    const float* edges      = (const float*)d_in[1];
    const int*   senders    = (const int*)d_in[2];
    const int*   receivers  = (const int*)d_in[3];
    const int*   node_graph = (const int*)d_in[4];
    const float* We1 = (const float*)d_in[5];
    const float* be1 = (const float*)d_in[6];
    const float* Wn1 = (const float*)d_in[7];
    const float* bn1 = (const float*)d_in[8];
    const float* We2 = (const float*)d_in[9];
    const float* be2 = (const float*)d_in[10];
    const float* Wn2 = (const float*)d_in[11];
    const float* bn2 = (const float*)d_in[12];
    const float* Wg2 = (const float*)d_in[13];
    const float* bg2 = (const float*)d_in[14];
    const float* He_e = (const float*)d_in[15];
    const float* He_s = (const float*)d_in[16];
    const float* He_g = (const float*)d_in[17];
    const float* He_b = (const float*)d_in[18];
    const float* Hn_n = (const float*)d_in[19];
    const float* Hn_in = (const float*)d_in[20];
    const float* Hn_g = (const float*)d_in[21];
    const float* Hn_b = (const float*)d_in[22];
    const float* Hg_e = (const float*)d_in[23];
    const float* Hg_n = (const float*)d_in[24];
    const float* Hg_g = (const float*)d_in[25];
    const float* Hg_b = (const float*)d_in[26];
    const float* Rn   = (const float*)d_in[27];
    const float* Rn_b = (const float*)d_in[28];
    const float* Rg   = (const float*)d_in[29];
    const float* Rg_b = (const float*)d_in[30];
    float* out = (float*)d_out;

    // ---- workspace layout (all chunks 16B-aligned) ----
    char* p = (char*)d_ws;
    uint4* rec2    = (uint4*)p;  p += (size_t)NEDGES * 32;           // 102.4 MB {e1, spack}
    uint4* e4      = (uint4*)p;  p += (size_t)NEDGES * 16;           // 51.2 MB (fp16 e2)
    int*   spack   = (int*)p;    p += (size_t)NEDGES * 4;            // 12.8 MB
    float* nbufA   = (float*)p;  p += (size_t)NNODES * 16 * 4;       // 12.8 MB
    float* nbufB   = (float*)p;  p += (size_t)NNODES * 16 * 4;       // 12.8 MB
    uint4* pprojA  = (uint4*)p;  p += (size_t)NNODES * 16;           // 3.2 MB (fp16 n@He_s)
    uint4* pprojB  = (uint4*)p;  p += (size_t)NNODES * 16;           // 3.2 MB (double buffer)
    int*   deg     = (int*)p;    p += (size_t)NNODES * 4;            // zero region start
    int*   ecnt    = (int*)p;    p += (size_t)NG * 4;
    float* gsum_e  = (float*)p;  p += (size_t)NG * 8 * 4;            // zero region end
    int*   off     = (int*)p;    p += (size_t)(NNODES + 4) * 4;
    int*   cursor  = (int*)p;    p += (size_t)NNODES * 4;
    int*   goff    = (int*)p;    p += (size_t)(NG + 4) * 4;
    int*   bsum    = (int*)p;    p += (size_t)NB1 * 4 + 8;
    int*   bpre    = (int*)p;    p += (size_t)NB1 * 4 + 8;
    int*   rstart  = (int*)p;    p += (size_t)(NB + 7) * 4;
    float* gsum_n  = (float*)p;  p += (size_t)NG * 16 * 4;
    float* g       = (float*)p;  p += (size_t)NG * 4 * 4;
    float* ghe     = (float*)p;  p += (size_t)NG * 8 * 4;
    float* ghn     = (float*)p;  p += (size_t)NG * 16 * 4;

    hipMemsetAsync(deg, 0, ((size_t)NNODES + NG + NG * 8) * 4, stream);

    // ---- CSR offsets ----
    k_deg<<<1024, 256, 0, stream>>>(receivers, deg);
    k_scan1<<<NB1, 256, 0, stream>>>(deg, bsum);
    k_scan2<<<1, 64, 0, stream>>>(bsum, bpre);
    k_scan3<<<NB1, 256, 0, stream>>>(deg, bpre, off, cursor);
    k_aux<<<(NNODES + 255) / 256, 256, 0, stream>>>(node_graph, off, goff, rstart);

    // ---- node/global encoders ----
    k_node_enc<<<(NNODES + 255) / 256, 256, 0, stream>>>(nodes, Wn1, bn1, Wn2, bn2, He_s,
                                                         nbufA, pprojA);
    k_gsum_nodes<<<NG, 256, 0, stream>>>(nbufA, goff, gsum_n);
    k_g_enc<<<1, NG, 0, stream>>>(gsum_n, goff, Wg2, bg2, He_g, He_b, Hn_g, Hn_b,
                                  g, ghe, ghn);

    // ---- perm + encode + hop-1 edge update (reads pprojA) ----
    k_perm_enc<<<1024, 256, 0, stream>>>(edges, receivers, senders, node_graph,
                                         We1, be1, We2, be2, He_e, pprojA, ghe,
                                         cursor, rec2, ecnt, gsum_e);

    // ---- hop 1 (node phase only; writes pprojB = proj(n1)) ----
    k_hop<0><<<NB, 256, 0, stream>>>(rec2, spack, off, rstart, node_graph,
                                     e4, pprojA, pprojB, nbufA, nbufB, ghe, ghn,
                                     He_e, He_s, Hn_n, Hn_in, gsum_e, Rn, Rn_b, out);
    k_gsum_nodes<<<NG, 256, 0, stream>>>(nbufB, goff, gsum_n);
    k_g_hop<<<1, NG, 0, stream>>>(g, gsum_e, gsum_n, ecnt, goff, Hg_e, Hg_n, Hg_g, Hg_b,
                                  He_g, He_b, Hn_g, Hn_b, ghe, ghn, 0, Rg, Rg_b, out);
    // ---- hop 2 (reads pprojB, writes pprojA = proj(n2)) ----
    k_hop<1><<<NB, 256, 0, stream>>>(rec2, spack, off, rstart, node_graph,
                                     e4, pprojB, pprojA, nbufB, nbufA, ghe, ghn,
                                     He_e, He_s, Hn_n, Hn_in, gsum_e, Rn, Rn_b, out);
    k_gsum_nodes<<<NG, 256, 0, stream>>>(nbufA, goff, gsum_n);
    k_g_hop<<<1, NG, 0, stream>>>(g, gsum_e, gsum_n, ecnt, goff, Hg_e, Hg_n, Hg_g, Hg_b,
                                  He_g, He_b, Hn_g, Hn_b, ghe, ghn, 0, Rg, Rg_b, out);
    // ---- hop 3 (reads pprojA; fused node readout) ----
    k_hop<2><<<NB, 256, 0, stream>>>(rec2, spack, off, rstart, node_graph,
                                     e4, pprojA, pprojB, nbufA, nbufB, ghe, ghn,
                                     He_e, He_s, Hn_n, Hn_in, gsum_e, Rn, Rn_b, out);
    k_gsum_nodes<<<NG, 256, 0, stream>>>(nbufB, goff, gsum_n);
    k_g_hop<<<1, NG, 0, stream>>>(g, gsum_e, gsum_n, ecnt, goff, Hg_e, Hg_n, Hg_g, Hg_b,
                                  He_g, He_b, Hn_g, Hn_b, ghe, ghn, 1, Rg, Rg_b, out);
}